// Round 7
// baseline (216.986 us; speedup 1.0000x reference)
//
#include <hip/hip_runtime.h>
#include <math.h>

#define NUM_GRAPHS 512
#define D 128
#define NEG 0.01f

typedef __attribute__((ext_vector_type(8)))  short    bf16x8;   // MFMA A/B frag (4 VGPR)
typedef __attribute__((ext_vector_type(16))) float    f32x16;   // MFMA C/D frag (32x32)
typedef __attribute__((ext_vector_type(2)))  int      i32x2;
typedef __attribute__((ext_vector_type(4)))  int      i32x4;

__device__ __forceinline__ unsigned short f2bf(float f) {
    unsigned u = __float_as_uint(f);
    u += 0x7fffu + ((u >> 16) & 1u);   // RNE
    return (unsigned short)(u >> 16);
}

// exchange: a.rows32-63 <-> b.rows0-31 across the lane<32/lane>=32 split
#if __has_builtin(__builtin_amdgcn_permlane32_swap)
#define PLSWAP(a, b) do {                                                     \
    i32x2 _r = __builtin_amdgcn_permlane32_swap((int)(a), (int)(b), false, false); \
    (a) = (unsigned)_r[0]; (b) = (unsigned)_r[1];                             \
} while (0)
#else
#define PLSWAP(a, b) asm volatile("v_permlane32_swap_b32 %0, %1" : "+v"(a), "+v"(b))
#endif

#define GLD16(gsrc, ldst)                                                    \
    __builtin_amdgcn_global_load_lds(                                        \
        (const __attribute__((address_space(1))) void*)(gsrc),               \
        (__attribute__((address_space(3))) void*)(ldst), 16, 0, 0)

// f32x8 -> bf16x8 via packed cvt (1 VALU per 2 elements)
__device__ __forceinline__ bf16x8 cvt8(float4 a, float4 b) {
    unsigned w0, w1, w2, w3;
    asm("v_cvt_pk_bf16_f32 %0, %1, %2" : "=v"(w0) : "v"(a.x), "v"(a.y));
    asm("v_cvt_pk_bf16_f32 %0, %1, %2" : "=v"(w1) : "v"(a.z), "v"(a.w));
    asm("v_cvt_pk_bf16_f32 %0, %1, %2" : "=v"(w2) : "v"(b.x), "v"(b.y));
    asm("v_cvt_pk_bf16_f32 %0, %1, %2" : "=v"(w3) : "v"(b.z), "v"(b.w));
    i32x4 v; v[0] = (int)w0; v[1] = (int)w1; v[2] = (int)w2; v[3] = (int)w3;
    return __builtin_bit_cast(bf16x8, v);
}

// ---------------------------------------------------------------------------
// Kernel 1: per-graph segment max+mean (pure pooling; no X copy anymore).
// grid=(NUM_GRAPHS,2) [y:0=topo,1=geom], block=256, 2-row unrolled for ILP.
// pooled[g*512 + t*256 + {0..127:max,128..255:mean}]
// ---------------------------------------------------------------------------
__global__ __launch_bounds__(256) void pool_kernel(
    const float* __restrict__ h_topo, const float* __restrict__ h_geom,
    const int* __restrict__ batch, int N, float* __restrict__ pooled)
{
    const int g = blockIdx.x, t = blockIdx.y;
    const float* __restrict__ h = t ? h_geom : h_topo;

    int lo = 0, hi = N;
    while (lo < hi) { int m = (lo + hi) >> 1; if (batch[m] < g) lo = m + 1; else hi = m; }
    const int start = lo; hi = N;
    while (lo < hi) { int m = (lo + hi) >> 1; if (batch[m] < g + 1) lo = m + 1; else hi = m; }
    const int end = lo;

    const int c = threadIdx.x & 31;   // float4 column
    const int r = threadIdx.x >> 5;   // 0..7 row phase

    float4 mx  = make_float4(-INFINITY, -INFINITY, -INFINITY, -INFINITY);
    float4 mx2 = mx;
    float4 sm  = make_float4(0.f, 0.f, 0.f, 0.f);
    float4 sm2 = sm;

    int row = start + r;
    for (; row + 8 < end; row += 16) {
        float4 v = *(const float4*)(h + (size_t)row * D + c * 4);
        float4 w = *(const float4*)(h + (size_t)(row + 8) * D + c * 4);
        mx.x  = fmaxf(mx.x,  v.x); mx.y  = fmaxf(mx.y,  v.y);
        mx.z  = fmaxf(mx.z,  v.z); mx.w  = fmaxf(mx.w,  v.w);
        sm.x += v.x; sm.y += v.y; sm.z += v.z; sm.w += v.w;
        mx2.x = fmaxf(mx2.x, w.x); mx2.y = fmaxf(mx2.y, w.y);
        mx2.z = fmaxf(mx2.z, w.z); mx2.w = fmaxf(mx2.w, w.w);
        sm2.x += w.x; sm2.y += w.y; sm2.z += w.z; sm2.w += w.w;
    }
    if (row < end) {
        float4 v = *(const float4*)(h + (size_t)row * D + c * 4);
        mx.x  = fmaxf(mx.x,  v.x); mx.y  = fmaxf(mx.y,  v.y);
        mx.z  = fmaxf(mx.z,  v.z); mx.w  = fmaxf(mx.w,  v.w);
        sm.x += v.x; sm.y += v.y; sm.z += v.z; sm.w += v.w;
    }
    mx.x = fmaxf(mx.x, mx2.x); mx.y = fmaxf(mx.y, mx2.y);
    mx.z = fmaxf(mx.z, mx2.z); mx.w = fmaxf(mx.w, mx2.w);
    sm.x += sm2.x; sm.y += sm2.y; sm.z += sm2.z; sm.w += sm2.w;

    __shared__ float4 smx[256], ssm[256];
    smx[threadIdx.x] = mx; ssm[threadIdx.x] = sm;
    __syncthreads();
    #pragma unroll
    for (int s = 4; s > 0; s >>= 1) {
        if (r < s) {
            float4 a = smx[threadIdx.x + s * 32];
            float4 b = ssm[threadIdx.x + s * 32];
            float4 m0 = smx[threadIdx.x];
            float4 s0 = ssm[threadIdx.x];
            m0.x = fmaxf(m0.x, a.x); m0.y = fmaxf(m0.y, a.y);
            m0.z = fmaxf(m0.z, a.z); m0.w = fmaxf(m0.w, a.w);
            s0.x += b.x; s0.y += b.y; s0.z += b.z; s0.w += b.w;
            smx[threadIdx.x] = m0; ssm[threadIdx.x] = s0;
        }
        __syncthreads();
    }
    if (r == 0) {
        float4 m0 = smx[threadIdx.x], s0 = ssm[threadIdx.x];
        const float inv = 1.0f / fmaxf((float)(end - start), 1.0f);
        float4 mean = make_float4(s0.x * inv, s0.y * inv, s0.z * inv, s0.w * inv);
        if (end <= start) { m0 = make_float4(0,0,0,0); mean = make_float4(0,0,0,0); }
        float* dst = pooled + (size_t)g * 512 + t * 256;
        *(float4*)(dst + c * 4)       = m0;
        *(float4*)(dst + 128 + c * 4) = mean;
    }
}

// ---------------------------------------------------------------------------
// Kernel 2: per-graph bias P[g][j] = b1[j] + pooled[g] . W1[pooled rows][j]
// (exact f32 — folds 512 of the 768 K-dims outside the bf16 path)
// ---------------------------------------------------------------------------
__global__ __launch_bounds__(256) void pmat_kernel(
    const float* __restrict__ pooled, const float* __restrict__ W1,
    const float* __restrict__ b1, float* __restrict__ P)
{
    const int g = blockIdx.x;
    const int j = threadIdx.x;

    __shared__ float pl[512];
    pl[j]       = pooled[(size_t)g * 512 + j];
    pl[j + 256] = pooled[(size_t)g * 512 + 256 + j];
    __syncthreads();

    float acc = b1[j];
    #pragma unroll 8
    for (int k = 0; k < 256; ++k)          // t_max,t_mean -> W1 rows 128..383
        acc += pl[k] * W1[(size_t)(128 + k) * 256 + j];
    #pragma unroll 8
    for (int k = 0; k < 256; ++k)          // g_max,g_mean -> W1 rows 512..767
        acc += pl[256 + k] * W1[(size_t)(512 + k) * 256 + j];

    P[(size_t)g * 256 + j] = acc;
}

// ---------------------------------------------------------------------------
// Kernel 3: weight pre-convert.
// W1sw: the exact 128KB LDS image of W1T, XOR-swizzled so that the mlp's
//   ds_read_b128 of 32 consecutive c-rows is bank-spread:
//   image[c*256 + kx] = bf16(W1[kmap(kx ^ ((c&7)<<3))][c]),
//   kmap(k) = k<128 ? k : k+256   (topo rows 0..127, geom rows 384..511)
// W2bT[j][c] = bf16(W2[c][j])  (plain, streamed from L2 in GEMM2')
// ---------------------------------------------------------------------------
__global__ __launch_bounds__(256) void wconv_kernel(
    const float* __restrict__ W1, const float* __restrict__ W2,
    unsigned short* __restrict__ W1sw, unsigned short* __restrict__ W2bT)
{
    const int idx = blockIdx.x * 256 + threadIdx.x;
    if (idx < 256 * 256) {
        const int c  = idx >> 8, kx = idx & 255;
        const int k  = kx ^ ((c & 7) << 3);
        const int kk = (k < 128) ? k : (k + 256);
        W1sw[idx] = f2bf(W1[(size_t)kk * 256 + c]);
    } else {
        const int j = idx - 256 * 256;
        const int n = j >> 8, k = j & 255;
        W2bT[j] = f2bf(W2[(size_t)k * 128 + n]);
    }
}

// ---------------------------------------------------------------------------
// Kernel 4: transposed-dataflow MFMA MLP (round-5 math, fixed resourcing).
// Block = 512 threads (8 waves), owns 256 nodes; wave owns 32 nodes end-to-end.
// - W1T staged ONCE per block into 128KB LDS (swizzled image, GLD16 DMA)
// - X loaded f32 per-lane, converted in-reg (v_cvt_pk_bf16_f32)
// - GEMM1' HT[c][n] = W1T(LDS) . XT(regs) + P (C-in); even/odd-ks split accs
// - H kept as packed bf16 words in regs; LeakyReLU in-reg
// - GEMM2' OT[j][n] = W2T(global-stream) . HT(regs via permlane32_swap) + b2
// ONE barrier total; no cross-wave coupling afterwards.
// 32x32x16 frags: A row=l&31,k=(l>>5)*8+j; B col=l&31; D col=l&31,
//   row=(r&3)+8*(r>>2)+4*(l>>5)   [m74/m101; verified end-to-end in round 5]
// ---------------------------------------------------------------------------
__global__ __launch_bounds__(512, 2) void mlp_mfma(
    const float* __restrict__ h_topo, const float* __restrict__ h_geom,
    const int* __restrict__ batch, const float* __restrict__ P,
    const unsigned short* __restrict__ W1sw, const unsigned short* __restrict__ W2bT,
    const float* __restrict__ b2, float* __restrict__ out, int N)
{
    __shared__ unsigned short wl[256 * 256];   // 128 KB W1T swizzled image

    const int tid  = threadIdx.x;
    const int wave = tid >> 6, lane = tid & 63;
    const int ll   = lane & 31, hi = lane >> 5;

    // ---- stage W1 image: 16 x (512 threads x 16B) = 128KB, linear DMA ----
    #pragma unroll
    for (int i = 0; i < 16; ++i)
        GLD16(W1sw + (i * 512 + tid) * 8, wl + (i * 512 + tid) * 8);

    const int node0 = blockIdx.x * 256 + wave * 32 + ll;
    const int node  = min(node0, N - 1);

    // ---- X fragments: 16 x bf16x8 = 64 VGPR (reused by all 8 ct) ----
    bf16x8 xr[16];
    #pragma unroll
    for (int ks = 0; ks < 8; ++ks) {
        const float* p = h_topo + (size_t)node * D + ks * 16 + hi * 8;
        float4 a = *(const float4*)p;
        float4 b = *(const float4*)(p + 4);
        xr[ks] = cvt8(a, b);
    }
    #pragma unroll
    for (int ks = 0; ks < 8; ++ks) {
        const float* p = h_geom + (size_t)node * D + ks * 16 + hi * 8;
        float4 a = *(const float4*)p;
        float4 b = *(const float4*)(p + 4);
        xr[8 + ks] = cvt8(a, b);
    }

    const int g = batch[node];
    const float* Pg = P + (size_t)g * 256 + hi * 4;
    const int kxor = (ll & 7) << 3;

    asm volatile("s_waitcnt vmcnt(0)" ::: "memory");
    __builtin_amdgcn_s_barrier();          // W1 image ready; only barrier

    unsigned hw[64];   // HT as packed bf16 pairs (c-rows, col = own node)

    // ---- GEMM1' ----
    #pragma unroll
    for (int ct = 0; ct < 8; ++ct) {
        f32x16 acca, accb;
        {
            const float* pp = Pg + ct * 32;
            float4 p0 = *(const float4*)(pp);
            float4 p1 = *(const float4*)(pp + 8);
            float4 p2 = *(const float4*)(pp + 16);
            float4 p3 = *(const float4*)(pp + 24);
            acca[0]=p0.x;  acca[1]=p0.y;  acca[2]=p0.z;  acca[3]=p0.w;
            acca[4]=p1.x;  acca[5]=p1.y;  acca[6]=p1.z;  acca[7]=p1.w;
            acca[8]=p2.x;  acca[9]=p2.y;  acca[10]=p2.z; acca[11]=p2.w;
            acca[12]=p3.x; acca[13]=p3.y; acca[14]=p3.z; acca[15]=p3.w;
            #pragma unroll
            for (int i = 0; i < 16; ++i) accb[i] = 0.f;
        }
        const unsigned short* wrow = wl + (ct * 32 + ll) * 256;
        #pragma unroll
        for (int kp = 0; kp < 8; ++kp) {
            const int ka = (hi * 8 + (2 * kp)     * 16) ^ kxor;
            const int kb = (hi * 8 + (2 * kp + 1) * 16) ^ kxor;
            bf16x8 fa = *(const bf16x8*)(wrow + ka);
            bf16x8 fb = *(const bf16x8*)(wrow + kb);
            acca = __builtin_amdgcn_mfma_f32_32x32x16_bf16(fa, xr[2 * kp],     acca, 0, 0, 0);
            accb = __builtin_amdgcn_mfma_f32_32x32x16_bf16(fb, xr[2 * kp + 1], accb, 0, 0, 0);
        }
        // LeakyReLU + pack to bf16 pairs: hw[ct*8+i] = (c_{2i}, c_{2i+1})
        #pragma unroll
        for (int i = 0; i < 8; ++i) {
            float va = acca[2 * i]     + accb[2 * i];
            float vb = acca[2 * i + 1] + accb[2 * i + 1];
            va = fmaxf(va, NEG * va);
            vb = fmaxf(vb, NEG * vb);
            unsigned w;
            asm("v_cvt_pk_bf16_f32 %0, %1, %2" : "=v"(w) : "v"(va), "v"(vb));
            hw[ct * 8 + i] = w;
        }
    }

    // ---- GEMM2' ----
    #pragma unroll
    for (int jt = 0; jt < 4; ++jt) {
        f32x16 acca, accb;
        {
            const float* bp = b2 + jt * 32 + hi * 4;
            float4 q0 = *(const float4*)(bp);
            float4 q1 = *(const float4*)(bp + 8);
            float4 q2 = *(const float4*)(bp + 16);
            float4 q3 = *(const float4*)(bp + 24);
            acca[0]=q0.x;  acca[1]=q0.y;  acca[2]=q0.z;  acca[3]=q0.w;
            acca[4]=q1.x;  acca[5]=q1.y;  acca[6]=q1.z;  acca[7]=q1.w;
            acca[8]=q2.x;  acca[9]=q2.y;  acca[10]=q2.z; acca[11]=q2.w;
            acca[12]=q3.x; acca[13]=q3.y; acca[14]=q3.z; acca[15]=q3.w;
            #pragma unroll
            for (int i = 0; i < 16; ++i) accb[i] = 0.f;
        }
        const unsigned short* wp = W2bT + (size_t)(jt * 32 + ll) * 256 + hi * 8;
        #pragma unroll
        for (int ks = 0; ks < 16; ++ks) {
            bf16x8 afr = *(const bf16x8*)(wp + ks * 16);
            // B-frag: HT rows c = ks*16 .. ks*16+15 at own node column
            const int b = (ks >> 1) * 8 + (ks & 1) * 4;
            unsigned wA = hw[b], wB = hw[b + 1], wC = hw[b + 2], wD = hw[b + 3];
            PLSWAP(wA, wC);   // wA = b0 (c0c1|c8c9),   wC = b2 (c4c5|c12c13)
            PLSWAP(wB, wD);   // wB = b1 (c2c3|c10c11), wD = b3 (c6c7|c14c15)
            i32x4 fw; fw[0] = (int)wA; fw[1] = (int)wB; fw[2] = (int)wC; fw[3] = (int)wD;
            bf16x8 bfr = __builtin_bit_cast(bf16x8, fw);
            if (ks & 1)
                accb = __builtin_amdgcn_mfma_f32_32x32x16_bf16(afr, bfr, accb, 0, 0, 0);
            else
                acca = __builtin_amdgcn_mfma_f32_32x32x16_bf16(afr, bfr, acca, 0, 0, 0);
        }
        if (node0 < N) {
            float* op = out + (size_t)node * 128 + jt * 32 + hi * 4;
            *(float4*)(op)      = make_float4(acca[0] + accb[0],  acca[1] + accb[1],
                                              acca[2] + accb[2],  acca[3] + accb[3]);
            *(float4*)(op + 8)  = make_float4(acca[4] + accb[4],  acca[5] + accb[5],
                                              acca[6] + accb[6],  acca[7] + accb[7]);
            *(float4*)(op + 16) = make_float4(acca[8] + accb[8],  acca[9] + accb[9],
                                              acca[10] + accb[10], acca[11] + accb[11]);
            *(float4*)(op + 24) = make_float4(acca[12] + accb[12], acca[13] + accb[13],
                                              acca[14] + accb[14], acca[15] + accb[15]);
        }
    }
}

// ---------------------------------------------------------------------------
extern "C" void kernel_launch(void* const* d_in, const int* in_sizes, int n_in,
                              void* d_out, int out_size, void* d_ws, size_t ws_size,
                              hipStream_t stream)
{
    const float* h_topo = (const float*)d_in[0];
    const float* h_geom = (const float*)d_in[1];
    const int*   batch  = (const int*)  d_in[2];
    const float* W1     = (const float*)d_in[3];
    const float* b1     = (const float*)d_in[4];
    const float* W2     = (const float*)d_in[5];
    const float* b2     = (const float*)d_in[6];
    float* out = (float*)d_out;

    const int N = in_sizes[0] / D;   // 200000

    float*          pooled = (float*)d_ws;                          // 512*512 f32
    float*          P      = pooled + (size_t)NUM_GRAPHS * 512;     // 512*256 f32
    unsigned short* W1sw   = (unsigned short*)(P + (size_t)NUM_GRAPHS * 256); // 64K ushort
    unsigned short* W2bT   = W1sw + 256 * 256;                      // 32K ushort

    wconv_kernel<<<(256 * 256 + 128 * 256) / 256, 256, 0, stream>>>(W1, W2, W1sw, W2bT);
    pool_kernel<<<dim3(NUM_GRAPHS, 2), 256, 0, stream>>>(h_topo, h_geom, batch, N, pooled);
    pmat_kernel<<<NUM_GRAPHS, 256, 0, stream>>>(pooled, W1, b1, P);

    const int nblocks = (N + 255) / 256;   // 782
    mlp_mfma<<<nblocks, 512, 0, stream>>>(h_topo, h_geom, batch, P,
                                          W1sw, W2bT, b2, out, N);
}

// Round 8
// 212.540 us; speedup vs baseline: 1.0209x; 1.0209x over previous
//
#include <hip/hip_runtime.h>
#include <math.h>

#define NUM_GRAPHS 512
#define D 128
#define NEG 0.01f
#define BN 64   // nodes per tile / block in MFMA MLP kernel
#define NS 4    // pool row-slices per (graph, tensor)

typedef __attribute__((ext_vector_type(8))) short  bf16x8;  // MFMA A/B frag
typedef __attribute__((ext_vector_type(4))) float  f32x4;   // MFMA C/D frag

__device__ __forceinline__ unsigned short f2bf(float f) {
    unsigned u = __float_as_uint(f);
    u += 0x7fffu + ((u >> 16) & 1u);   // RNE
    return (unsigned short)(u >> 16);
}

__device__ __forceinline__ uint2 pack4(float4 v) {
    uint2 pk;
    pk.x = (unsigned)f2bf(v.x) | ((unsigned)f2bf(v.y) << 16);
    pk.y = (unsigned)f2bf(v.z) | ((unsigned)f2bf(v.w) << 16);
    return pk;
}

// swizzled ushort index within a 64x256 tile: row*256 + (k ^ ((row&7)<<3))
__device__ __forceinline__ int swz(int row, int k) {
    return row * 256 + (k ^ ((row & 7) << 3));
}

#define GLD16(gsrc, ldst)                                                    \
    __builtin_amdgcn_global_load_lds(                                        \
        (const __attribute__((address_space(1))) void*)(gsrc),               \
        (__attribute__((address_space(3))) void*)(ldst), 16, 0, 0)

// raw barrier that does NOT drain vmcnt (keeps global prefetch in flight);
// lgkmcnt(0) publishes LDS writes / retires LDS reads.
#define LDS_BARRIER()                                                        \
    do {                                                                     \
        asm volatile("s_waitcnt lgkmcnt(0)" ::: "memory");                   \
        __builtin_amdgcn_s_barrier();                                        \
        asm volatile("" ::: "memory");                                       \
    } while (0)

// ---------------------------------------------------------------------------
// Kernel 1: sliced per-graph segment max+sum partials AND bf16 tile-blocked
// pre-swizzled copy of X. grid=(512, 2, NS) [y: tensor, z: row-slice].
// pp[((g*2+t)*NS+s)*256 + {0..127: max, 128..255: sum}]
// ---------------------------------------------------------------------------
__global__ __launch_bounds__(256) void pool_kernel(
    const float* __restrict__ h_topo, const float* __restrict__ h_geom,
    const int* __restrict__ batch, int N, float* __restrict__ pp,
    unsigned short* __restrict__ xt)
{
    const int g = blockIdx.x, t = blockIdx.y, s = blockIdx.z;
    const float* __restrict__ h = t ? h_geom : h_topo;
    const int koff = t ? 128 : 0;

    int lo = 0, hi = N;
    while (lo < hi) { int m = (lo + hi) >> 1; if (batch[m] < g) lo = m + 1; else hi = m; }
    const int start = lo; hi = N;
    while (lo < hi) { int m = (lo + hi) >> 1; if (batch[m] < g + 1) lo = m + 1; else hi = m; }
    const int end = lo;

    // this block's row slice
    const int len = end - start;
    const int r0  = start + (int)(((long long)len * s) / NS);
    const int r1  = start + (int)(((long long)len * (s + 1)) / NS);

    const int c = threadIdx.x & 31;   // float4 column
    const int r = threadIdx.x >> 5;   // 0..7 row phase
    const int kk = koff + c * 4;

    float4 mx  = make_float4(-INFINITY, -INFINITY, -INFINITY, -INFINITY);
    float4 mx2 = mx;
    float4 sm  = make_float4(0.f, 0.f, 0.f, 0.f);
    float4 sm2 = sm;

    int row = r0 + r;
    for (; row + 8 < r1; row += 16) {
        float4 v = *(const float4*)(h + (size_t)row * D + c * 4);
        float4 w = *(const float4*)(h + (size_t)(row + 8) * D + c * 4);
        mx.x  = fmaxf(mx.x,  v.x); mx.y  = fmaxf(mx.y,  v.y);
        mx.z  = fmaxf(mx.z,  v.z); mx.w  = fmaxf(mx.w,  v.w);
        sm.x += v.x; sm.y += v.y; sm.z += v.z; sm.w += v.w;
        mx2.x = fmaxf(mx2.x, w.x); mx2.y = fmaxf(mx2.y, w.y);
        mx2.z = fmaxf(mx2.z, w.z); mx2.w = fmaxf(mx2.w, w.w);
        sm2.x += w.x; sm2.y += w.y; sm2.z += w.z; sm2.w += w.w;
        *(uint2*)(xt + (size_t)(row >> 6) * 16384 + swz(row & 63, kk)) = pack4(v);
        *(uint2*)(xt + (size_t)((row + 8) >> 6) * 16384 + swz((row + 8) & 63, kk)) = pack4(w);
    }
    if (row < r1) {
        float4 v = *(const float4*)(h + (size_t)row * D + c * 4);
        mx.x  = fmaxf(mx.x,  v.x); mx.y  = fmaxf(mx.y,  v.y);
        mx.z  = fmaxf(mx.z,  v.z); mx.w  = fmaxf(mx.w,  v.w);
        sm.x += v.x; sm.y += v.y; sm.z += v.z; sm.w += v.w;
        *(uint2*)(xt + (size_t)(row >> 6) * 16384 + swz(row & 63, kk)) = pack4(v);
    }
    mx.x = fmaxf(mx.x, mx2.x); mx.y = fmaxf(mx.y, mx2.y);
    mx.z = fmaxf(mx.z, mx2.z); mx.w = fmaxf(mx.w, mx2.w);
    sm.x += sm2.x; sm.y += sm2.y; sm.z += sm2.z; sm.w += sm2.w;

    __shared__ float4 smx[256], ssm[256];
    smx[threadIdx.x] = mx; ssm[threadIdx.x] = sm;
    __syncthreads();
    #pragma unroll
    for (int st = 4; st > 0; st >>= 1) {
        if (r < st) {
            float4 a = smx[threadIdx.x + st * 32];
            float4 b = ssm[threadIdx.x + st * 32];
            float4 m0 = smx[threadIdx.x];
            float4 s0 = ssm[threadIdx.x];
            m0.x = fmaxf(m0.x, a.x); m0.y = fmaxf(m0.y, a.y);
            m0.z = fmaxf(m0.z, a.z); m0.w = fmaxf(m0.w, a.w);
            s0.x += b.x; s0.y += b.y; s0.z += b.z; s0.w += b.w;
            smx[threadIdx.x] = m0; ssm[threadIdx.x] = s0;
        }
        __syncthreads();
    }
    if (r == 0) {
        float* dst = pp + ((size_t)(g * 2 + t) * NS + s) * 256;
        *(float4*)(dst + c * 4)       = smx[threadIdx.x];   // raw max partial
        *(float4*)(dst + 128 + c * 4) = ssm[threadIdx.x];   // raw sum partial
    }
}

// ---------------------------------------------------------------------------
// Kernel 2: finalize partials + per-graph bias
// P[g][j] = b1[j] + pooled[g] . W1[pooled rows][j]
// ---------------------------------------------------------------------------
__global__ __launch_bounds__(256) void pmat_kernel(
    const float* __restrict__ pp, const int* __restrict__ batch, int N,
    const float* __restrict__ W1, const float* __restrict__ b1,
    float* __restrict__ P)
{
    const int g = blockIdx.x;
    const int j = threadIdx.x;

    int lo = 0, hi = N;
    while (lo < hi) { int m = (lo + hi) >> 1; if (batch[m] < g) lo = m + 1; else hi = m; }
    const int start = lo; hi = N;
    while (lo < hi) { int m = (lo + hi) >> 1; if (batch[m] < g + 1) lo = m + 1; else hi = m; }
    const int end = lo;
    const float inv   = 1.0f / fmaxf((float)(end - start), 1.0f);
    const bool  empty = (end <= start);

    __shared__ float pl[512];
    #pragma unroll
    for (int e0 = 0; e0 < 2; ++e0) {
        const int e = j + e0 * 256;
        const int t = e >> 8, i = e & 255;
        const float* q = pp + (size_t)(g * 2 + t) * NS * 256 + i;
        float v;
        if (i < 128)
            v = fmaxf(fmaxf(q[0], q[256]), fmaxf(q[512], q[768]));
        else
            v = (q[0] + q[256] + q[512] + q[768]) * inv;
        pl[e] = empty ? 0.f : v;
    }
    __syncthreads();

    float acc = b1[j];
    #pragma unroll 8
    for (int k = 0; k < 256; ++k)          // t_max,t_mean -> W1 rows 128..383
        acc += pl[k] * W1[(size_t)(128 + k) * 256 + j];
    #pragma unroll 8
    for (int k = 0; k < 256; ++k)          // g_max,g_mean -> W1 rows 512..767
        acc += pl[256 + k] * W1[(size_t)(512 + k) * 256 + j];

    P[(size_t)g * 256 + j] = acc;
}

// ---------------------------------------------------------------------------
// Kernel 3: weight pre-convert to transposed bf16.
// ---------------------------------------------------------------------------
__global__ __launch_bounds__(256) void wconv_kernel(
    const float* __restrict__ W1, const float* __restrict__ W2,
    unsigned short* __restrict__ W1bT, unsigned short* __restrict__ W2bT)
{
    const int idx = blockIdx.x * 256 + threadIdx.x;
    if (idx < 256 * 256) {
        const int n = idx >> 8, k = idx & 255;
        const int kk = (k < 128) ? k : (k + 256);
        W1bT[idx] = f2bf(W1[(size_t)kk * 256 + n]);
    } else {
        const int j = idx - 256 * 256;
        if (j < 128 * 256) {
            const int n = j >> 8, k = j & 255;
            W2bT[j] = f2bf(W2[(size_t)k * 128 + n]);
        }
    }
}

// ---------------------------------------------------------------------------
// Kernel 4: fused MFMA MLP, DMA-staged, deep weight-register pipeline.
//  - stage X via global_load_lds(16B); W1 ks=0,1 preloaded alongside (drain
//    together with the stage at the first __syncthreads)
//  - GEMM1: 2-slot rotating W1 frags, prefetch distance 2 iters
//  - GEMM2: 4-slot W2 frags; ks=0..3 issued BEFORE the epilogue barriers
//    (in flight across them — barriers are lgkm-only), per-iter prefetch ks+4
// ---------------------------------------------------------------------------
__global__ __launch_bounds__(256, 3) void mlp_mfma(
    const unsigned short* __restrict__ xt, const int* __restrict__ batch,
    const float* __restrict__ P,
    const unsigned short* __restrict__ W1bT, const unsigned short* __restrict__ W2bT,
    const float* __restrict__ b2, float* __restrict__ out, int N)
{
    __shared__ unsigned short xs[64 * 256];   // 32 KB, X then H (swz layout)
    __shared__ int gid[64];

    const int tid  = threadIdx.x;
    const int wave = tid >> 6, lane = tid & 63;
    const int base = blockIdx.x * BN;
    const size_t tbase = (size_t)blockIdx.x * 16384;

    // ---- DMA stage: tile -> LDS, linear copy (2048 x 16B total) ----
    #pragma unroll
    for (int c = 0; c < 8; ++c) {
        const int off = wave * 4096 + c * 512;           // ushort units
        GLD16(xt + tbase + off + lane * 8, xs + off);
    }
    if (tid < 64) gid[tid] = batch[min(base + tid, N - 1)];

    const int g0 = batch[base];
    const int g1 = batch[min(base + 63, N - 1)];
    const bool uni = (g0 == g1);

    const int lhi = lane >> 4;   // 0..3
    const int llo = lane & 15;   // 0..15

    const unsigned short* w1p = W1bT + (size_t)(wave * 64 + llo) * 256 + lhi * 8;
    const unsigned short* w2p = W2bT + (size_t)(wave * 32 + llo) * 256 + lhi * 8;

    float pf[4];
    if (uni) {
        #pragma unroll
        for (int ct = 0; ct < 4; ++ct)
            pf[ct] = P[(size_t)g0 * 256 + wave * 64 + ct * 16 + llo];
    }

    // ---- preload GEMM1 ks=0,1 weight frags (hide under stage drain) ----
    bf16x8 bfr[2][4];
    #pragma unroll
    for (int ct = 0; ct < 4; ++ct) {
        bfr[0][ct] = *(const bf16x8*)(w1p + (size_t)ct * 16 * 256);
        bfr[1][ct] = *(const bf16x8*)(w1p + (size_t)ct * 16 * 256 + 32);
    }

    asm volatile("s_waitcnt vmcnt(0)" ::: "memory");
    __syncthreads();

    // ---- GEMM1, 2-slot pipeline, distance-2 prefetch ----
    f32x4 acc[4][4];
    #pragma unroll
    for (int rt = 0; rt < 4; ++rt)
        #pragma unroll
        for (int ct = 0; ct < 4; ++ct) {
            const float p = uni ? pf[ct] : 0.f;
            acc[rt][ct] = (f32x4){p, p, p, p};
        }

    #pragma unroll
    for (int ks = 0; ks < 8; ++ks) {
        const int kb = ks * 32 + lhi * 8;
        bf16x8 afr[4];
        #pragma unroll
        for (int rt = 0; rt < 4; ++rt)
            afr[rt] = *(const bf16x8*)&xs[swz(rt * 16 + llo, kb)];
        __builtin_amdgcn_s_setprio(1);
        #pragma unroll
        for (int rt = 0; rt < 4; ++rt)
            #pragma unroll
            for (int ct = 0; ct < 4; ++ct)
                acc[rt][ct] = __builtin_amdgcn_mfma_f32_16x16x32_bf16(
                    afr[rt], bfr[ks & 1][ct], acc[rt][ct], 0, 0, 0);
        __builtin_amdgcn_s_setprio(0);
        if (ks < 6) {   // slot just freed; lands 2 iters out
            const int kbn = (ks + 2) * 32;
            #pragma unroll
            for (int ct = 0; ct < 4; ++ct)
                bfr[ks & 1][ct] = *(const bf16x8*)(w1p + (size_t)ct * 16 * 256 + kbn);
        }
    }

    // ---- issue GEMM2 ks=0..3 weight frags (in flight across barriers) ----
    bf16x8 bfr2[4][2];
    #pragma unroll
    for (int k0 = 0; k0 < 4; ++k0)
        #pragma unroll
        for (int ct = 0; ct < 2; ++ct)
            bfr2[k0][ct] = *(const bf16x8*)(w2p + (size_t)ct * 16 * 256 + k0 * 32);

    LDS_BARRIER();   // all waves done reading X (lgkm only; vm stays pending)

    // ---- epilogue 1: (+P if boundary tile), LeakyReLU, H -> xs (bf16) ----
    #pragma unroll
    for (int rt = 0; rt < 4; ++rt) {
        #pragma unroll
        for (int ct = 0; ct < 4; ++ct) {
            const int col = wave * 64 + ct * 16 + llo;
            #pragma unroll
            for (int q = 0; q < 4; ++q) {
                const int row = rt * 16 + lhi * 4 + q;
                float v = acc[rt][ct][q];
                if (!uni) v += P[(size_t)gid[row] * 256 + col];
                v = fmaxf(v, NEG * v);   // LeakyReLU
                xs[swz(row, col)] = f2bf(v);
            }
        }
    }

    LDS_BARRIER();   // H published

    // ---- GEMM2, 4-slot pipeline, distance-4 prefetch ----
    f32x4 acc2[4][2];
    #pragma unroll
    for (int ct = 0; ct < 2; ++ct) {
        const float bv = b2[wave * 32 + ct * 16 + llo];
        #pragma unroll
        for (int rt = 0; rt < 4; ++rt)
            acc2[rt][ct] = (f32x4){bv, bv, bv, bv};
    }
    #pragma unroll
    for (int ks = 0; ks < 8; ++ks) {
        const int kb = ks * 32 + lhi * 8;
        bf16x8 afr[4];
        #pragma unroll
        for (int rt = 0; rt < 4; ++rt)
            afr[rt] = *(const bf16x8*)&xs[swz(rt * 16 + llo, kb)];
        __builtin_amdgcn_s_setprio(1);
        #pragma unroll
        for (int rt = 0; rt < 4; ++rt)
            #pragma unroll
            for (int ct = 0; ct < 2; ++ct)
                acc2[rt][ct] = __builtin_amdgcn_mfma_f32_16x16x32_bf16(
                    afr[rt], bfr2[ks & 3][ct], acc2[rt][ct], 0, 0, 0);
        __builtin_amdgcn_s_setprio(0);
        if (ks < 4) {
            const int kbn = (ks + 4) * 32;
            #pragma unroll
            for (int ct = 0; ct < 2; ++ct)
                bfr2[ks & 3][ct] = *(const bf16x8*)(w2p + (size_t)ct * 16 * 256 + kbn);
        }
    }

    // ---- store out (f32) ----
    #pragma unroll
    for (int rt = 0; rt < 4; ++rt)
        #pragma unroll
        for (int ct = 0; ct < 2; ++ct)
            #pragma unroll
            for (int q = 0; q < 4; ++q) {
                const int row  = rt * 16 + lhi * 4 + q;
                const int node = base + row;
                if (node < N)
                    out[(size_t)node * 128 + wave * 32 + ct * 16 + llo] = acc2[rt][ct][q];
            }
}

// ---------------------------------------------------------------------------
extern "C" void kernel_launch(void* const* d_in, const int* in_sizes, int n_in,
                              void* d_out, int out_size, void* d_ws, size_t ws_size,
                              hipStream_t stream)
{
    const float* h_topo = (const float*)d_in[0];
    const float* h_geom = (const float*)d_in[1];
    const int*   batch  = (const int*)  d_in[2];
    const float* W1     = (const float*)d_in[3];
    const float* b1     = (const float*)d_in[4];
    const float* W2     = (const float*)d_in[5];
    const float* b2     = (const float*)d_in[6];
    float* out = (float*)d_out;

    const int N = in_sizes[0] / D;   // 200000

    // ws layout: pp (512*2*NS*256 f32 = 4MB) | P (512KB) | W1bT | W2bT | xt
    float*          pp   = (float*)d_ws;
    float*          P    = pp + (size_t)NUM_GRAPHS * 2 * NS * 256;
    unsigned short* W1bT = (unsigned short*)(P + (size_t)NUM_GRAPHS * 256);
    unsigned short* W2bT = W1bT + 256 * 256;

    const size_t small_bytes = (size_t)NUM_GRAPHS * 2 * NS * 256 * 4
                             + (size_t)NUM_GRAPHS * 256 * 4
                             + (size_t)(256 * 256 + 128 * 256) * 2;   // ~4.7 MB
    const size_t xt_bytes = (size_t)N * 256 * 2;                       // 102.4 MB

    // xt: pre-swizzled bf16 tile copy of X. Prefer ws; else alias d_out
    // (tile t's xt bytes == tile t's out bytes; the owning block fully reads
    //  xt[t] before storing out[t], and pool regenerates xt every call).
    unsigned short* xt;
    if (ws_size >= small_bytes + xt_bytes)
        xt = (unsigned short*)((char*)d_ws + small_bytes);
    else
        xt = (unsigned short*)d_out;

    wconv_kernel<<<(256 * 256 + 128 * 256) / 256, 256, 0, stream>>>(W1, W2, W1bT, W2bT);
    pool_kernel<<<dim3(NUM_GRAPHS, 2, NS), 256, 0, stream>>>(h_topo, h_geom, batch, N,
                                                             pp, xt);
    pmat_kernel<<<NUM_GRAPHS, 256, 0, stream>>>(pp, batch, N, W1, b1, P);

    mlp_mfma<<<N / BN, 256, 0, stream>>>(xt, batch, P, W1bT, W2bT, b2, out, N);
}

// Round 9
// 205.871 us; speedup vs baseline: 1.0540x; 1.0324x over previous
//
#include <hip/hip_runtime.h>
#include <math.h>

#define NUM_GRAPHS 512
#define D 128
#define NEG 0.01f
#define BN 128  // nodes per block in MFMA MLP kernel (two 64-row xt tiles)
#define NS 4    // pool row-slices per (graph, tensor)

typedef __attribute__((ext_vector_type(8))) short  bf16x8;  // MFMA A/B frag
typedef __attribute__((ext_vector_type(4))) float  f32x4;   // MFMA C/D frag

__device__ __forceinline__ unsigned short f2bf(float f) {
    unsigned u = __float_as_uint(f);
    u += 0x7fffu + ((u >> 16) & 1u);   // RNE
    return (unsigned short)(u >> 16);
}

__device__ __forceinline__ uint2 pack4(float4 v) {
    uint2 pk;
    pk.x = (unsigned)f2bf(v.x) | ((unsigned)f2bf(v.y) << 16);
    pk.y = (unsigned)f2bf(v.z) | ((unsigned)f2bf(v.w) << 16);
    return pk;
}

// swizzled ushort index within a 64x256 tile: row*256 + (k ^ ((row&7)<<3))
__device__ __forceinline__ int swz(int row, int k) {
    return row * 256 + (k ^ ((row & 7) << 3));
}
// same, for a 128-row двух-tile LDS image (two stacked 64-row tiles)
__device__ __forceinline__ int swz128(int row, int k) {
    return (row >> 6) * 16384 + (row & 63) * 256 + (k ^ ((row & 7) << 3));
}

#define GLD16(gsrc, ldst)                                                    \
    __builtin_amdgcn_global_load_lds(                                        \
        (const __attribute__((address_space(1))) void*)(gsrc),               \
        (__attribute__((address_space(3))) void*)(ldst), 16, 0, 0)

// raw barrier that does NOT drain vmcnt (keeps global prefetch in flight);
// lgkmcnt(0) publishes LDS writes / retires LDS reads.
#define LDS_BARRIER()                                                        \
    do {                                                                     \
        asm volatile("s_waitcnt lgkmcnt(0)" ::: "memory");                   \
        __builtin_amdgcn_s_barrier();                                        \
        asm volatile("" ::: "memory");                                       \
    } while (0)

// ---------------------------------------------------------------------------
// Kernel 1: sliced per-graph segment max+sum partials AND bf16 tile-blocked
// pre-swizzled copy of X. grid=(512, 2, NS) [y: tensor, z: row-slice].
// pp[((g*2+t)*NS+s)*256 + {0..127: max, 128..255: sum}]
// ---------------------------------------------------------------------------
__global__ __launch_bounds__(256) void pool_kernel(
    const float* __restrict__ h_topo, const float* __restrict__ h_geom,
    const int* __restrict__ batch, int N, float* __restrict__ pp,
    unsigned short* __restrict__ xt)
{
    const int g = blockIdx.x, t = blockIdx.y, s = blockIdx.z;
    const float* __restrict__ h = t ? h_geom : h_topo;
    const int koff = t ? 128 : 0;

    int lo = 0, hi = N;
    while (lo < hi) { int m = (lo + hi) >> 1; if (batch[m] < g) lo = m + 1; else hi = m; }
    const int start = lo; hi = N;
    while (lo < hi) { int m = (lo + hi) >> 1; if (batch[m] < g + 1) lo = m + 1; else hi = m; }
    const int end = lo;

    const int len = end - start;
    const int r0  = start + (int)(((long long)len * s) / NS);
    const int r1  = start + (int)(((long long)len * (s + 1)) / NS);

    const int c = threadIdx.x & 31;   // float4 column
    const int r = threadIdx.x >> 5;   // 0..7 row phase
    const int kk = koff + c * 4;

    float4 mx  = make_float4(-INFINITY, -INFINITY, -INFINITY, -INFINITY);
    float4 mx2 = mx;
    float4 sm  = make_float4(0.f, 0.f, 0.f, 0.f);
    float4 sm2 = sm;

    int row = r0 + r;
    for (; row + 8 < r1; row += 16) {
        float4 v = *(const float4*)(h + (size_t)row * D + c * 4);
        float4 w = *(const float4*)(h + (size_t)(row + 8) * D + c * 4);
        mx.x  = fmaxf(mx.x,  v.x); mx.y  = fmaxf(mx.y,  v.y);
        mx.z  = fmaxf(mx.z,  v.z); mx.w  = fmaxf(mx.w,  v.w);
        sm.x += v.x; sm.y += v.y; sm.z += v.z; sm.w += v.w;
        mx2.x = fmaxf(mx2.x, w.x); mx2.y = fmaxf(mx2.y, w.y);
        mx2.z = fmaxf(mx2.z, w.z); mx2.w = fmaxf(mx2.w, w.w);
        sm2.x += w.x; sm2.y += w.y; sm2.z += w.z; sm2.w += w.w;
        *(uint2*)(xt + (size_t)(row >> 6) * 16384 + swz(row & 63, kk)) = pack4(v);
        *(uint2*)(xt + (size_t)((row + 8) >> 6) * 16384 + swz((row + 8) & 63, kk)) = pack4(w);
    }
    if (row < r1) {
        float4 v = *(const float4*)(h + (size_t)row * D + c * 4);
        mx.x  = fmaxf(mx.x,  v.x); mx.y  = fmaxf(mx.y,  v.y);
        mx.z  = fmaxf(mx.z,  v.z); mx.w  = fmaxf(mx.w,  v.w);
        sm.x += v.x; sm.y += v.y; sm.z += v.z; sm.w += v.w;
        *(uint2*)(xt + (size_t)(row >> 6) * 16384 + swz(row & 63, kk)) = pack4(v);
    }
    mx.x = fmaxf(mx.x, mx2.x); mx.y = fmaxf(mx.y, mx2.y);
    mx.z = fmaxf(mx.z, mx2.z); mx.w = fmaxf(mx.w, mx2.w);
    sm.x += sm2.x; sm.y += sm2.y; sm.z += sm2.z; sm.w += sm2.w;

    __shared__ float4 smx[256], ssm[256];
    smx[threadIdx.x] = mx; ssm[threadIdx.x] = sm;
    __syncthreads();
    #pragma unroll
    for (int st = 4; st > 0; st >>= 1) {
        if (r < st) {
            float4 a = smx[threadIdx.x + st * 32];
            float4 b = ssm[threadIdx.x + st * 32];
            float4 m0 = smx[threadIdx.x];
            float4 s0 = ssm[threadIdx.x];
            m0.x = fmaxf(m0.x, a.x); m0.y = fmaxf(m0.y, a.y);
            m0.z = fmaxf(m0.z, a.z); m0.w = fmaxf(m0.w, a.w);
            s0.x += b.x; s0.y += b.y; s0.z += b.z; s0.w += b.w;
            smx[threadIdx.x] = m0; ssm[threadIdx.x] = s0;
        }
        __syncthreads();
    }
    if (r == 0) {
        float* dst = pp + ((size_t)(g * 2 + t) * NS + s) * 256;
        *(float4*)(dst + c * 4)       = smx[threadIdx.x];   // raw max partial
        *(float4*)(dst + 128 + c * 4) = ssm[threadIdx.x];   // raw sum partial
    }
}

// ---------------------------------------------------------------------------
// Kernel 2: finalize partials + per-graph bias
// P[g][j] = b1[j] + pooled[g] . W1[pooled rows][j]
// ---------------------------------------------------------------------------
__global__ __launch_bounds__(256) void pmat_kernel(
    const float* __restrict__ pp, const int* __restrict__ batch, int N,
    const float* __restrict__ W1, const float* __restrict__ b1,
    float* __restrict__ P)
{
    const int g = blockIdx.x;
    const int j = threadIdx.x;

    int lo = 0, hi = N;
    while (lo < hi) { int m = (lo + hi) >> 1; if (batch[m] < g) lo = m + 1; else hi = m; }
    const int start = lo; hi = N;
    while (lo < hi) { int m = (lo + hi) >> 1; if (batch[m] < g + 1) lo = m + 1; else hi = m; }
    const int end = lo;
    const float inv   = 1.0f / fmaxf((float)(end - start), 1.0f);
    const bool  empty = (end <= start);

    __shared__ float pl[512];
    #pragma unroll
    for (int e0 = 0; e0 < 2; ++e0) {
        const int e = j + e0 * 256;
        const int t = e >> 8, i = e & 255;
        const float* q = pp + (size_t)(g * 2 + t) * NS * 256 + i;
        float v;
        if (i < 128)
            v = fmaxf(fmaxf(q[0], q[256]), fmaxf(q[512], q[768]));
        else
            v = (q[0] + q[256] + q[512] + q[768]) * inv;
        pl[e] = empty ? 0.f : v;
    }
    __syncthreads();

    float acc = b1[j];
    #pragma unroll 8
    for (int k = 0; k < 256; ++k)          // t_max,t_mean -> W1 rows 128..383
        acc += pl[k] * W1[(size_t)(128 + k) * 256 + j];
    #pragma unroll 8
    for (int k = 0; k < 256; ++k)          // g_max,g_mean -> W1 rows 512..767
        acc += pl[256 + k] * W1[(size_t)(512 + k) * 256 + j];

    P[(size_t)g * 256 + j] = acc;
}

// ---------------------------------------------------------------------------
// Kernel 3: weight pre-convert to transposed bf16.
// ---------------------------------------------------------------------------
__global__ __launch_bounds__(256) void wconv_kernel(
    const float* __restrict__ W1, const float* __restrict__ W2,
    unsigned short* __restrict__ W1bT, unsigned short* __restrict__ W2bT)
{
    const int idx = blockIdx.x * 256 + threadIdx.x;
    if (idx < 256 * 256) {
        const int n = idx >> 8, k = idx & 255;
        const int kk = (k < 128) ? k : (k + 256);
        W1bT[idx] = f2bf(W1[(size_t)kk * 256 + n]);
    } else {
        const int j = idx - 256 * 256;
        if (j < 128 * 256) {
            const int n = j >> 8, k = j & 255;
            W2bT[j] = f2bf(W2[(size_t)k * 128 + n]);
        }
    }
}

// ---------------------------------------------------------------------------
// Kernel 4: fused MFMA MLP. 128 nodes/block, 8 waves (512 thr).
// W1/W2 read from L2 ONCE per 128 nodes (was per 64) -> W L2 traffic halved.
// Wave w owns H cols [32w, 32w+32) in GEMM1 (ct=2) and out cols [16w, 16w+16)
// in GEMM2. X/H share one 64KB LDS tile (two stacked 64-row swizzled tiles).
// ---------------------------------------------------------------------------
__global__ __launch_bounds__(512, 4) void mlp_mfma(
    const unsigned short* __restrict__ xt, const int* __restrict__ batch,
    const float* __restrict__ P,
    const unsigned short* __restrict__ W1bT, const unsigned short* __restrict__ W2bT,
    const float* __restrict__ b2, float* __restrict__ out, int N)
{
    __shared__ unsigned short xs[128 * 256];   // 64 KB, X then H (swz128 layout)
    __shared__ int gid[128];

    const int tid  = threadIdx.x;
    const int wave = tid >> 6, lane = tid & 63;
    const int base = blockIdx.x * BN;
    const size_t tbase = (size_t)blockIdx.x * 32768;

    // ---- DMA stage: 2 xt tiles -> LDS (4096 x 16B); tail block: 1 tile ----
    const int nchunk = (base + 64 < N) ? 8 : 4;
    for (int c = 0; c < nchunk; ++c) {
        const int off = (c * 512 + tid) * 8;             // ushort units
        GLD16(xt + tbase + off, xs + off);
    }
    if (tid < 128) gid[tid] = batch[min(base + tid, N - 1)];

    const int g0 = batch[base];
    const int g1 = batch[min(base + 127, N - 1)];
    const bool uni = (g0 == g1);

    const int lhi = lane >> 4;   // 0..3
    const int llo = lane & 15;   // 0..15

    const unsigned short* w1p = W1bT + (size_t)(wave * 32 + llo) * 256 + lhi * 8;
    const unsigned short* w2p = W2bT + (size_t)(wave * 16 + llo) * 256 + lhi * 8;

    float pf[2];
    if (uni) {
        #pragma unroll
        for (int ct = 0; ct < 2; ++ct)
            pf[ct] = P[(size_t)g0 * 256 + wave * 32 + ct * 16 + llo];
    }

    // ---- preload GEMM1 ks=0,1 weight frags (hide under stage drain) ----
    bf16x8 bfr[2][2];
    #pragma unroll
    for (int ct = 0; ct < 2; ++ct) {
        bfr[0][ct] = *(const bf16x8*)(w1p + (size_t)ct * 16 * 256);
        bfr[1][ct] = *(const bf16x8*)(w1p + (size_t)ct * 16 * 256 + 32);
    }

    asm volatile("s_waitcnt vmcnt(0)" ::: "memory");
    __syncthreads();

    // ---- GEMM1: 8 row-tiles x 2 col-tiles, dist-2 W prefetch ----
    f32x4 acc[8][2];
    #pragma unroll
    for (int rt = 0; rt < 8; ++rt)
        #pragma unroll
        for (int ct = 0; ct < 2; ++ct) {
            const float p = uni ? pf[ct] : 0.f;
            acc[rt][ct] = (f32x4){p, p, p, p};
        }

    #pragma unroll
    for (int ks = 0; ks < 8; ++ks) {
        const int kb = ks * 32 + lhi * 8;
        bf16x8 afr[8];
        #pragma unroll
        for (int rt = 0; rt < 8; ++rt)
            afr[rt] = *(const bf16x8*)&xs[swz128(rt * 16 + llo, kb)];
        __builtin_amdgcn_s_setprio(1);
        #pragma unroll
        for (int rt = 0; rt < 8; ++rt)
            #pragma unroll
            for (int ct = 0; ct < 2; ++ct)
                acc[rt][ct] = __builtin_amdgcn_mfma_f32_16x16x32_bf16(
                    afr[rt], bfr[ks & 1][ct], acc[rt][ct], 0, 0, 0);
        __builtin_amdgcn_s_setprio(0);
        if (ks < 6) {
            const int kbn = (ks + 2) * 32;
            #pragma unroll
            for (int ct = 0; ct < 2; ++ct)
                bfr[ks & 1][ct] = *(const bf16x8*)(w1p + (size_t)ct * 16 * 256 + kbn);
        }
    }

    // ---- issue GEMM2 ks=0,1 weight frags (in flight across barriers) ----
    bf16x8 bfr2[2];
    bfr2[0] = *(const bf16x8*)(w2p);
    bfr2[1] = *(const bf16x8*)(w2p + 32);

    LDS_BARRIER();   // all waves done reading X (lgkm only; vm stays pending)

    // ---- epilogue 1: (+P if boundary tile), LeakyReLU, H -> xs (bf16) ----
    #pragma unroll
    for (int rt = 0; rt < 8; ++rt) {
        #pragma unroll
        for (int ct = 0; ct < 2; ++ct) {
            const int col = wave * 32 + ct * 16 + llo;
            #pragma unroll
            for (int q = 0; q < 4; ++q) {
                const int row = rt * 16 + lhi * 4 + q;
                float v = acc[rt][ct][q];
                if (!uni) v += P[(size_t)gid[row] * 256 + col];
                v = fmaxf(v, NEG * v);   // LeakyReLU
                xs[swz128(row, col)] = f2bf(v);
            }
        }
    }

    LDS_BARRIER();   // H published

    // ---- GEMM2: 8 row-tiles x 1 col-tile (16 cols/wave), dist-2 prefetch ----
    f32x4 acc2[8];
    {
        const float bv = b2[wave * 16 + llo];
        #pragma unroll
        for (int rt = 0; rt < 8; ++rt)
            acc2[rt] = (f32x4){bv, bv, bv, bv};
    }
    #pragma unroll
    for (int ks = 0; ks < 8; ++ks) {
        const int kb = ks * 32 + lhi * 8;
        bf16x8 afr[8];
        #pragma unroll
        for (int rt = 0; rt < 8; ++rt)
            afr[rt] = *(const bf16x8*)&xs[swz128(rt * 16 + llo, kb)];
        __builtin_amdgcn_s_setprio(1);
        #pragma unroll
        for (int rt = 0; rt < 8; ++rt)
            acc2[rt] = __builtin_amdgcn_mfma_f32_16x16x32_bf16(
                afr[rt], bfr2[ks & 1], acc2[rt], 0, 0, 0);
        __builtin_amdgcn_s_setprio(0);
        if (ks < 6)
            bfr2[ks & 1] = *(const bf16x8*)(w2p + (ks + 2) * 32);
    }

    // ---- store out (f32) ----
    #pragma unroll
    for (int rt = 0; rt < 8; ++rt)
        #pragma unroll
        for (int q = 0; q < 4; ++q) {
            const int row  = rt * 16 + lhi * 4 + q;
            const int node = base + row;
            if (node < N)
                out[(size_t)node * 128 + wave * 16 + llo] = acc2[rt][q];
        }
}

// ---------------------------------------------------------------------------
extern "C" void kernel_launch(void* const* d_in, const int* in_sizes, int n_in,
                              void* d_out, int out_size, void* d_ws, size_t ws_size,
                              hipStream_t stream)
{
    const float* h_topo = (const float*)d_in[0];
    const float* h_geom = (const float*)d_in[1];
    const int*   batch  = (const int*)  d_in[2];
    const float* W1     = (const float*)d_in[3];
    const float* b1     = (const float*)d_in[4];
    const float* W2     = (const float*)d_in[5];
    const float* b2     = (const float*)d_in[6];
    float* out = (float*)d_out;

    const int N = in_sizes[0] / D;   // 200000

    // ws layout: pp (512*2*NS*256 f32 = 4MB) | P (512KB) | W1bT | W2bT | xt
    float*          pp   = (float*)d_ws;
    float*          P    = pp + (size_t)NUM_GRAPHS * 2 * NS * 256;
    unsigned short* W1bT = (unsigned short*)(P + (size_t)NUM_GRAPHS * 256);
    unsigned short* W2bT = W1bT + 256 * 256;

    const size_t small_bytes = (size_t)NUM_GRAPHS * 2 * NS * 256 * 4
                             + (size_t)NUM_GRAPHS * 256 * 4
                             + (size_t)(256 * 256 + 128 * 256) * 2;   // ~4.7 MB
    const size_t xt_bytes = (size_t)N * 256 * 2;                       // 102.4 MB

    // xt: pre-swizzled bf16 tile copy of X. Prefer ws; else alias d_out
    // (block b's xt tiles 2b,2b+1 == block b's out rows; fully read at the
    //  first barrier before any store, and pool regenerates xt every call).
    unsigned short* xt;
    if (ws_size >= small_bytes + xt_bytes)
        xt = (unsigned short*)((char*)d_ws + small_bytes);
    else
        xt = (unsigned short*)d_out;

    wconv_kernel<<<(256 * 256 + 128 * 256) / 256, 256, 0, stream>>>(W1, W2, W1bT, W2bT);
    pool_kernel<<<dim3(NUM_GRAPHS, 2, NS), 256, 0, stream>>>(h_topo, h_geom, batch, N,
                                                             pp, xt);
    pmat_kernel<<<NUM_GRAPHS, 256, 0, stream>>>(pp, batch, N, W1, b1, P);

    const int nblocks = (N + BN - 1) / BN;   // 1563
    mlp_mfma<<<nblocks, 512, 0, stream>>>(xt, batch, P, W1bT, W2bT, b2, out, N);
}

// Round 10
// 199.992 us; speedup vs baseline: 1.0850x; 1.0294x over previous
//
#include <hip/hip_runtime.h>
#include <math.h>

#define NUM_GRAPHS 512
#define D 128
#define NEG 0.01f
#define BN 128  // nodes per block in MFMA MLP kernel (two 64-row xt tiles)
#define NS 4    // pool row-slices per (graph, tensor)

typedef __attribute__((ext_vector_type(8))) short  bf16x8;  // MFMA A/B frag
typedef __attribute__((ext_vector_type(4))) float  f32x4;   // MFMA C/D frag

__device__ __forceinline__ unsigned short f2bf(float f) {
    unsigned u = __float_as_uint(f);
    u += 0x7fffu + ((u >> 16) & 1u);   // RNE
    return (unsigned short)(u >> 16);
}

__device__ __forceinline__ uint2 pack4(float4 v) {
    uint2 pk;
    pk.x = (unsigned)f2bf(v.x) | ((unsigned)f2bf(v.y) << 16);
    pk.y = (unsigned)f2bf(v.z) | ((unsigned)f2bf(v.w) << 16);
    return pk;
}

// swizzled ushort index within a 64x256 tile: row*256 + (k ^ ((row&7)<<3))
__device__ __forceinline__ int swz(int row, int k) {
    return row * 256 + (k ^ ((row & 7) << 3));
}
// same, for a 128-row two-tile LDS image (two stacked 64-row tiles)
__device__ __forceinline__ int swz128(int row, int k) {
    return (row >> 6) * 16384 + (row & 63) * 256 + (k ^ ((row & 7) << 3));
}

#define GLD16(gsrc, ldst)                                                    \
    __builtin_amdgcn_global_load_lds(                                        \
        (const __attribute__((address_space(1))) void*)(gsrc),               \
        (__attribute__((address_space(3))) void*)(ldst), 16, 0, 0)

// raw barrier that does NOT drain vmcnt (keeps global prefetch in flight);
// lgkmcnt(0) publishes LDS writes / retires LDS reads.
#define LDS_BARRIER()                                                        \
    do {                                                                     \
        asm volatile("s_waitcnt lgkmcnt(0)" ::: "memory");                   \
        __builtin_amdgcn_s_barrier();                                        \
        asm volatile("" ::: "memory");                                       \
    } while (0)

#define FMAX4(a, b)                                                          \
    do {                                                                     \
        (a).x = fmaxf((a).x, (b).x); (a).y = fmaxf((a).y, (b).y);            \
        (a).z = fmaxf((a).z, (b).z); (a).w = fmaxf((a).w, (b).w);            \
    } while (0)
#define FADD4(a, b)                                                          \
    do {                                                                     \
        (a).x += (b).x; (a).y += (b).y; (a).z += (b).z; (a).w += (b).w;      \
    } while (0)

// ---------------------------------------------------------------------------
// Kernel 0: segment bounds. seg[g] = lower_bound(batch, g), g in [0, 512].
// Removes the per-block dependent-load binary-search chains from pool/pmat.
// ---------------------------------------------------------------------------
__global__ __launch_bounds__(256) void bounds_kernel(
    const int* __restrict__ batch, int N, int* __restrict__ seg)
{
    const int g = blockIdx.x * 256 + threadIdx.x;
    if (g <= NUM_GRAPHS) {
        int lo = 0, hi = N;
        while (lo < hi) { int m = (lo + hi) >> 1; if (batch[m] < g) lo = m + 1; else hi = m; }
        seg[g] = lo;
    }
}

// ---------------------------------------------------------------------------
// Kernel 1: sliced per-graph segment max+sum partials AND bf16 tile-blocked
// pre-swizzled copy of X. grid=(512, 2, NS) [y: tensor, z: row-slice].
// pp[((g*2+t)*NS+s)*256 + {0..127: max, 128..255: sum}]
// 4 independent load/acc streams per iteration (32 rows/step) for MLP.
// ---------------------------------------------------------------------------
__global__ __launch_bounds__(256) void pool_kernel(
    const float* __restrict__ h_topo, const float* __restrict__ h_geom,
    const int* __restrict__ seg, int N, float* __restrict__ pp,
    unsigned short* __restrict__ xt)
{
    const int g = blockIdx.x, t = blockIdx.y, s = blockIdx.z;
    const float* __restrict__ h = t ? h_geom : h_topo;
    const int koff = t ? 128 : 0;

    const int start = seg[g], end = seg[g + 1];
    const int len = end - start;
    const int r0  = start + (int)(((long long)len * s) / NS);
    const int r1  = start + (int)(((long long)len * (s + 1)) / NS);

    const int c = threadIdx.x & 31;   // float4 column
    const int r = threadIdx.x >> 5;   // 0..7 row phase
    const int kk = koff + c * 4;

    float4 mxA = make_float4(-INFINITY, -INFINITY, -INFINITY, -INFINITY);
    float4 mxB = mxA, mxC = mxA, mxD = mxA;
    float4 smA = make_float4(0.f, 0.f, 0.f, 0.f);
    float4 smB = smA, smC = smA, smD = smA;

    int row = r0 + r;
    for (; row + 24 < r1; row += 32) {
        float4 v0 = *(const float4*)(h + (size_t)row * D + c * 4);
        float4 v1 = *(const float4*)(h + (size_t)(row + 8)  * D + c * 4);
        float4 v2 = *(const float4*)(h + (size_t)(row + 16) * D + c * 4);
        float4 v3 = *(const float4*)(h + (size_t)(row + 24) * D + c * 4);
        FMAX4(mxA, v0); FADD4(smA, v0);
        FMAX4(mxB, v1); FADD4(smB, v1);
        FMAX4(mxC, v2); FADD4(smC, v2);
        FMAX4(mxD, v3); FADD4(smD, v3);
        *(uint2*)(xt + (size_t)(row >> 6) * 16384 + swz(row & 63, kk)) = pack4(v0);
        *(uint2*)(xt + (size_t)((row + 8)  >> 6) * 16384 + swz((row + 8)  & 63, kk)) = pack4(v1);
        *(uint2*)(xt + (size_t)((row + 16) >> 6) * 16384 + swz((row + 16) & 63, kk)) = pack4(v2);
        *(uint2*)(xt + (size_t)((row + 24) >> 6) * 16384 + swz((row + 24) & 63, kk)) = pack4(v3);
    }
    for (; row < r1; row += 8) {
        float4 v = *(const float4*)(h + (size_t)row * D + c * 4);
        FMAX4(mxA, v); FADD4(smA, v);
        *(uint2*)(xt + (size_t)(row >> 6) * 16384 + swz(row & 63, kk)) = pack4(v);
    }
    FMAX4(mxA, mxB); FMAX4(mxC, mxD); FMAX4(mxA, mxC);
    FADD4(smA, smB); FADD4(smC, smD); FADD4(smA, smC);

    __shared__ float4 smx[256], ssm[256];
    smx[threadIdx.x] = mxA; ssm[threadIdx.x] = smA;
    __syncthreads();
    #pragma unroll
    for (int st = 4; st > 0; st >>= 1) {
        if (r < st) {
            float4 a = smx[threadIdx.x + st * 32];
            float4 b = ssm[threadIdx.x + st * 32];
            float4 m0 = smx[threadIdx.x];
            float4 s0 = ssm[threadIdx.x];
            FMAX4(m0, a); FADD4(s0, b);
            smx[threadIdx.x] = m0; ssm[threadIdx.x] = s0;
        }
        __syncthreads();
    }
    if (r == 0) {
        float* dst = pp + ((size_t)(g * 2 + t) * NS + s) * 256;
        *(float4*)(dst + c * 4)       = smx[threadIdx.x];   // raw max partial
        *(float4*)(dst + 128 + c * 4) = ssm[threadIdx.x];   // raw sum partial
    }
}

// ---------------------------------------------------------------------------
// Kernel 2: finalize partials + per-graph bias
// P[g][j] = b1[j] + pooled[g] . W1[pooled rows][j]
// ---------------------------------------------------------------------------
__global__ __launch_bounds__(256) void pmat_kernel(
    const float* __restrict__ pp, const int* __restrict__ seg,
    const float* __restrict__ W1, const float* __restrict__ b1,
    float* __restrict__ P)
{
    const int g = blockIdx.x;
    const int j = threadIdx.x;

    const int start = seg[g], end = seg[g + 1];
    const float inv   = 1.0f / fmaxf((float)(end - start), 1.0f);
    const bool  empty = (end <= start);

    __shared__ float pl[512];
    #pragma unroll
    for (int e0 = 0; e0 < 2; ++e0) {
        const int e = j + e0 * 256;
        const int t = e >> 8, i = e & 255;
        const float* q = pp + (size_t)(g * 2 + t) * NS * 256 + i;
        float v;
        if (i < 128)
            v = fmaxf(fmaxf(q[0], q[256]), fmaxf(q[512], q[768]));
        else
            v = (q[0] + q[256] + q[512] + q[768]) * inv;
        pl[e] = empty ? 0.f : v;
    }
    __syncthreads();

    float acc = b1[j];
    #pragma unroll 8
    for (int k = 0; k < 256; ++k)          // t_max,t_mean -> W1 rows 128..383
        acc += pl[k] * W1[(size_t)(128 + k) * 256 + j];
    #pragma unroll 8
    for (int k = 0; k < 256; ++k)          // g_max,g_mean -> W1 rows 512..767
        acc += pl[256 + k] * W1[(size_t)(512 + k) * 256 + j];

    P[(size_t)g * 256 + j] = acc;
}

// ---------------------------------------------------------------------------
// Kernel 3: weight pre-convert to transposed bf16.
// ---------------------------------------------------------------------------
__global__ __launch_bounds__(256) void wconv_kernel(
    const float* __restrict__ W1, const float* __restrict__ W2,
    unsigned short* __restrict__ W1bT, unsigned short* __restrict__ W2bT)
{
    const int idx = blockIdx.x * 256 + threadIdx.x;
    if (idx < 256 * 256) {
        const int n = idx >> 8, k = idx & 255;
        const int kk = (k < 128) ? k : (k + 256);
        W1bT[idx] = f2bf(W1[(size_t)kk * 256 + n]);
    } else {
        const int j = idx - 256 * 256;
        if (j < 128 * 256) {
            const int n = j >> 8, k = j & 255;
            W2bT[j] = f2bf(W2[(size_t)k * 128 + n]);
        }
    }
}

// ---------------------------------------------------------------------------
// Kernel 4: fused MFMA MLP. 128 nodes/block, 8 waves (512 thr).
// W1/W2 read from L2 ONCE per 128 nodes. Wave w owns H cols [32w, 32w+32)
// in GEMM1 and out cols [16w, 16w+16) in GEMM2. X/H share one 64KB LDS tile.
// ---------------------------------------------------------------------------
__global__ __launch_bounds__(512, 4) void mlp_mfma(
    const unsigned short* __restrict__ xt, const int* __restrict__ batch,
    const float* __restrict__ P,
    const unsigned short* __restrict__ W1bT, const unsigned short* __restrict__ W2bT,
    const float* __restrict__ b2, float* __restrict__ out, int N)
{
    __shared__ unsigned short xs[128 * 256];   // 64 KB, X then H (swz128 layout)
    __shared__ int gid[128];

    const int tid  = threadIdx.x;
    const int wave = tid >> 6, lane = tid & 63;
    const int base = blockIdx.x * BN;
    const size_t tbase = (size_t)blockIdx.x * 32768;

    // ---- DMA stage: 2 xt tiles -> LDS (4096 x 16B); tail block: 1 tile ----
    const int nchunk = (base + 64 < N) ? 8 : 4;
    for (int c = 0; c < nchunk; ++c) {
        const int off = (c * 512 + tid) * 8;             // ushort units
        GLD16(xt + tbase + off, xs + off);
    }
    if (tid < 128) gid[tid] = batch[min(base + tid, N - 1)];

    const int g0 = batch[base];
    const int g1 = batch[min(base + 127, N - 1)];
    const bool uni = (g0 == g1);

    const int lhi = lane >> 4;   // 0..3
    const int llo = lane & 15;   // 0..15

    const unsigned short* w1p = W1bT + (size_t)(wave * 32 + llo) * 256 + lhi * 8;
    const unsigned short* w2p = W2bT + (size_t)(wave * 16 + llo) * 256 + lhi * 8;

    float pf[2];
    if (uni) {
        #pragma unroll
        for (int ct = 0; ct < 2; ++ct)
            pf[ct] = P[(size_t)g0 * 256 + wave * 32 + ct * 16 + llo];
    }

    // ---- preload GEMM1 ks=0,1 weight frags (hide under stage drain) ----
    bf16x8 bfr[2][2];
    #pragma unroll
    for (int ct = 0; ct < 2; ++ct) {
        bfr[0][ct] = *(const bf16x8*)(w1p + (size_t)ct * 16 * 256);
        bfr[1][ct] = *(const bf16x8*)(w1p + (size_t)ct * 16 * 256 + 32);
    }

    asm volatile("s_waitcnt vmcnt(0)" ::: "memory");
    __syncthreads();

    // ---- GEMM1: 8 row-tiles x 2 col-tiles, dist-2 W prefetch ----
    f32x4 acc[8][2];
    #pragma unroll
    for (int rt = 0; rt < 8; ++rt)
        #pragma unroll
        for (int ct = 0; ct < 2; ++ct) {
            const float p = uni ? pf[ct] : 0.f;
            acc[rt][ct] = (f32x4){p, p, p, p};
        }

    #pragma unroll
    for (int ks = 0; ks < 8; ++ks) {
        const int kb = ks * 32 + lhi * 8;
        bf16x8 afr[8];
        #pragma unroll
        for (int rt = 0; rt < 8; ++rt)
            afr[rt] = *(const bf16x8*)&xs[swz128(rt * 16 + llo, kb)];
        __builtin_amdgcn_s_setprio(1);
        #pragma unroll
        for (int rt = 0; rt < 8; ++rt)
            #pragma unroll
            for (int ct = 0; ct < 2; ++ct)
                acc[rt][ct] = __builtin_amdgcn_mfma_f32_16x16x32_bf16(
                    afr[rt], bfr[ks & 1][ct], acc[rt][ct], 0, 0, 0);
        __builtin_amdgcn_s_setprio(0);
        if (ks < 6) {
            const int kbn = (ks + 2) * 32;
            #pragma unroll
            for (int ct = 0; ct < 2; ++ct)
                bfr[ks & 1][ct] = *(const bf16x8*)(w1p + (size_t)ct * 16 * 256 + kbn);
        }
    }

    // ---- issue GEMM2 ks=0,1 weight frags (in flight across barriers) ----
    bf16x8 bfr2[2];
    bfr2[0] = *(const bf16x8*)(w2p);
    bfr2[1] = *(const bf16x8*)(w2p + 32);

    LDS_BARRIER();   // all waves done reading X (lgkm only; vm stays pending)

    // ---- epilogue 1: (+P if boundary tile), LeakyReLU, H -> xs (bf16) ----
    #pragma unroll
    for (int rt = 0; rt < 8; ++rt) {
        #pragma unroll
        for (int ct = 0; ct < 2; ++ct) {
            const int col = wave * 32 + ct * 16 + llo;
            #pragma unroll
            for (int q = 0; q < 4; ++q) {
                const int row = rt * 16 + lhi * 4 + q;
                float v = acc[rt][ct][q];
                if (!uni) v += P[(size_t)gid[row] * 256 + col];
                v = fmaxf(v, NEG * v);   // LeakyReLU
                xs[swz128(row, col)] = f2bf(v);
            }
        }
    }

    LDS_BARRIER();   // H published

    // ---- GEMM2: 8 row-tiles x 1 col-tile (16 cols/wave), dist-2 prefetch ----
    f32x4 acc2[8];
    {
        const float bv = b2[wave * 16 + llo];
        #pragma unroll
        for (int rt = 0; rt < 8; ++rt)
            acc2[rt] = (f32x4){bv, bv, bv, bv};
    }
    #pragma unroll
    for (int ks = 0; ks < 8; ++ks) {
        const int kb = ks * 32 + lhi * 8;
        bf16x8 afr[8];
        #pragma unroll
        for (int rt = 0; rt < 8; ++rt)
            afr[rt] = *(const bf16x8*)&xs[swz128(rt * 16 + llo, kb)];
        __builtin_amdgcn_s_setprio(1);
        #pragma unroll
        for (int rt = 0; rt < 8; ++rt)
            acc2[rt] = __builtin_amdgcn_mfma_f32_16x16x32_bf16(
                afr[rt], bfr2[ks & 1], acc2[rt], 0, 0, 0);
        __builtin_amdgcn_s_setprio(0);
        if (ks < 6)
            bfr2[ks & 1] = *(const bf16x8*)(w2p + (ks + 2) * 32);
    }

    // ---- store out (f32) ----
    #pragma unroll
    for (int rt = 0; rt < 8; ++rt)
        #pragma unroll
        for (int q = 0; q < 4; ++q) {
            const int row  = rt * 16 + lhi * 4 + q;
            const int node = base + row;
            if (node < N)
                out[(size_t)node * 128 + wave * 16 + llo] = acc2[rt][q];
        }
}

// ---------------------------------------------------------------------------
extern "C" void kernel_launch(void* const* d_in, const int* in_sizes, int n_in,
                              void* d_out, int out_size, void* d_ws, size_t ws_size,
                              hipStream_t stream)
{
    const float* h_topo = (const float*)d_in[0];
    const float* h_geom = (const float*)d_in[1];
    const int*   batch  = (const int*)  d_in[2];
    const float* W1     = (const float*)d_in[3];
    const float* b1     = (const float*)d_in[4];
    const float* W2     = (const float*)d_in[5];
    const float* b2     = (const float*)d_in[6];
    float* out = (float*)d_out;

    const int N = in_sizes[0] / D;   // 200000

    // ws layout: pp (4MB) | P (512KB) | W1bT | W2bT | seg (4KB) | xt
    float*          pp   = (float*)d_ws;
    float*          P    = pp + (size_t)NUM_GRAPHS * 2 * NS * 256;
    unsigned short* W1bT = (unsigned short*)(P + (size_t)NUM_GRAPHS * 256);
    unsigned short* W2bT = W1bT + 256 * 256;
    int*            seg  = (int*)(W2bT + 128 * 256);

    const size_t small_bytes = (size_t)NUM_GRAPHS * 2 * NS * 256 * 4
                             + (size_t)NUM_GRAPHS * 256 * 4
                             + (size_t)(256 * 256 + 128 * 256) * 2
                             + 1024 * 4;                               // ~4.7 MB
    const size_t xt_bytes = (size_t)N * 256 * 2;                       // 102.4 MB

    // xt: pre-swizzled bf16 tile copy of X. Prefer ws; else alias d_out
    // (block b's xt tiles 2b,2b+1 == block b's out rows; fully read at the
    //  first barrier before any store, and pool regenerates xt every call).
    unsigned short* xt;
    if (ws_size >= small_bytes + xt_bytes)
        xt = (unsigned short*)((char*)d_ws + small_bytes);
    else
        xt = (unsigned short*)d_out;

    bounds_kernel<<<3, 256, 0, stream>>>(batch, N, seg);
    wconv_kernel<<<(256 * 256 + 128 * 256) / 256, 256, 0, stream>>>(W1, W2, W1bT, W2bT);
    pool_kernel<<<dim3(NUM_GRAPHS, 2, NS), 256, 0, stream>>>(h_topo, h_geom, seg, N,
                                                             pp, xt);
    pmat_kernel<<<NUM_GRAPHS, 256, 0, stream>>>(pp, seg, W1, b1, P);

    const int nblocks = (N + BN - 1) / BN;   // 1563
    mlp_mfma<<<nblocks, 512, 0, stream>>>(xt, batch, P, W1bT, W2bT, b2, out, N);
}

// Round 11
// 192.678 us; speedup vs baseline: 1.1262x; 1.0380x over previous
//
#include <hip/hip_runtime.h>
#include <math.h>

#define NUM_GRAPHS 512
#define D 128
#define NEG 0.01f
#define BN 128  // nodes per block in MFMA MLP kernel
#define NS 4    // pool row-slices per (graph, tensor)

typedef __attribute__((ext_vector_type(8))) short  bf16x8;  // MFMA A/B frag
typedef __attribute__((ext_vector_type(4))) float  f32x4;   // MFMA C/D frag
typedef __attribute__((ext_vector_type(4))) int    i32x4;

__device__ __forceinline__ unsigned short f2bf(float f) {
    unsigned u = __float_as_uint(f);
    u += 0x7fffu + ((u >> 16) & 1u);   // RNE
    return (unsigned short)(u >> 16);
}

// f32x8 -> 16B of bf16 via packed cvt
__device__ __forceinline__ bf16x8 cvt8(float4 a, float4 b) {
    unsigned w0, w1, w2, w3;
    asm("v_cvt_pk_bf16_f32 %0, %1, %2" : "=v"(w0) : "v"(a.x), "v"(a.y));
    asm("v_cvt_pk_bf16_f32 %0, %1, %2" : "=v"(w1) : "v"(a.z), "v"(a.w));
    asm("v_cvt_pk_bf16_f32 %0, %1, %2" : "=v"(w2) : "v"(b.x), "v"(b.y));
    asm("v_cvt_pk_bf16_f32 %0, %1, %2" : "=v"(w3) : "v"(b.z), "v"(b.w));
    i32x4 v; v[0] = (int)w0; v[1] = (int)w1; v[2] = (int)w2; v[3] = (int)w3;
    return __builtin_bit_cast(bf16x8, v);
}

// swizzled ushort index in the 128-row two-tile LDS image
__device__ __forceinline__ int swz128(int row, int k) {
    return (row >> 6) * 16384 + (row & 63) * 256 + (k ^ ((row & 7) << 3));
}

// raw barrier that does NOT drain vmcnt (keeps global prefetch in flight);
// lgkmcnt(0) publishes LDS writes / retires LDS reads.
#define LDS_BARRIER()                                                        \
    do {                                                                     \
        asm volatile("s_waitcnt lgkmcnt(0)" ::: "memory");                   \
        __builtin_amdgcn_s_barrier();                                        \
        asm volatile("" ::: "memory");                                       \
    } while (0)

#define FMAX4(a, b)                                                          \
    do {                                                                     \
        (a).x = fmaxf((a).x, (b).x); (a).y = fmaxf((a).y, (b).y);            \
        (a).z = fmaxf((a).z, (b).z); (a).w = fmaxf((a).w, (b).w);            \
    } while (0)
#define FADD4(a, b)                                                          \
    do {                                                                     \
        (a).x += (b).x; (a).y += (b).y; (a).z += (b).z; (a).w += (b).w;      \
    } while (0)

// ---------------------------------------------------------------------------
// Kernel 0: segment bounds. seg[g] = lower_bound(batch, g), g in [0, 512].
// ---------------------------------------------------------------------------
__global__ __launch_bounds__(256) void bounds_kernel(
    const int* __restrict__ batch, int N, int* __restrict__ seg)
{
    const int g = blockIdx.x * 256 + threadIdx.x;
    if (g <= NUM_GRAPHS) {
        int lo = 0, hi = N;
        while (lo < hi) { int m = (lo + hi) >> 1; if (batch[m] < g) lo = m + 1; else hi = m; }
        seg[g] = lo;
    }
}

// ---------------------------------------------------------------------------
// Kernel 1: sliced per-graph segment max+sum partials (pure reduction — the
// xt copy is gone). grid=(512, 2, NS); 4 independent acc streams for MLP.
// pp[((g*2+t)*NS+s)*256 + {0..127: max, 128..255: sum}]
// ---------------------------------------------------------------------------
__global__ __launch_bounds__(256) void pool_kernel(
    const float* __restrict__ h_topo, const float* __restrict__ h_geom,
    const int* __restrict__ seg, int N, float* __restrict__ pp)
{
    const int g = blockIdx.x, t = blockIdx.y, s = blockIdx.z;
    const float* __restrict__ h = t ? h_geom : h_topo;

    const int start = seg[g], end = seg[g + 1];
    const int len = end - start;
    const int r0  = start + (int)(((long long)len * s) / NS);
    const int r1  = start + (int)(((long long)len * (s + 1)) / NS);

    const int c = threadIdx.x & 31;   // float4 column
    const int r = threadIdx.x >> 5;   // 0..7 row phase

    float4 mxA = make_float4(-INFINITY, -INFINITY, -INFINITY, -INFINITY);
    float4 mxB = mxA, mxC = mxA, mxD = mxA;
    float4 smA = make_float4(0.f, 0.f, 0.f, 0.f);
    float4 smB = smA, smC = smA, smD = smA;

    int row = r0 + r;
    for (; row + 24 < r1; row += 32) {
        float4 v0 = *(const float4*)(h + (size_t)row * D + c * 4);
        float4 v1 = *(const float4*)(h + (size_t)(row + 8)  * D + c * 4);
        float4 v2 = *(const float4*)(h + (size_t)(row + 16) * D + c * 4);
        float4 v3 = *(const float4*)(h + (size_t)(row + 24) * D + c * 4);
        FMAX4(mxA, v0); FADD4(smA, v0);
        FMAX4(mxB, v1); FADD4(smB, v1);
        FMAX4(mxC, v2); FADD4(smC, v2);
        FMAX4(mxD, v3); FADD4(smD, v3);
    }
    for (; row < r1; row += 8) {
        float4 v = *(const float4*)(h + (size_t)row * D + c * 4);
        FMAX4(mxA, v); FADD4(smA, v);
    }
    FMAX4(mxA, mxB); FMAX4(mxC, mxD); FMAX4(mxA, mxC);
    FADD4(smA, smB); FADD4(smC, smD); FADD4(smA, smC);

    __shared__ float4 smx[256], ssm[256];
    smx[threadIdx.x] = mxA; ssm[threadIdx.x] = smA;
    __syncthreads();
    #pragma unroll
    for (int st = 4; st > 0; st >>= 1) {
        if (r < st) {
            float4 a = smx[threadIdx.x + st * 32];
            float4 b = ssm[threadIdx.x + st * 32];
            float4 m0 = smx[threadIdx.x];
            float4 s0 = ssm[threadIdx.x];
            FMAX4(m0, a); FADD4(s0, b);
            smx[threadIdx.x] = m0; ssm[threadIdx.x] = s0;
        }
        __syncthreads();
    }
    if (r == 0) {
        float* dst = pp + ((size_t)(g * 2 + t) * NS + s) * 256;
        *(float4*)(dst + c * 4)       = smx[threadIdx.x];   // raw max partial
        *(float4*)(dst + 128 + c * 4) = ssm[threadIdx.x];   // raw sum partial
    }
}

// ---------------------------------------------------------------------------
// Kernel 2: finalize partials + per-graph bias
// P[g][j] = b1[j] + pooled[g] . W1[pooled rows][j]
// ---------------------------------------------------------------------------
__global__ __launch_bounds__(256) void pmat_kernel(
    const float* __restrict__ pp, const int* __restrict__ seg,
    const float* __restrict__ W1, const float* __restrict__ b1,
    float* __restrict__ P)
{
    const int g = blockIdx.x;
    const int j = threadIdx.x;

    const int start = seg[g], end = seg[g + 1];
    const float inv   = 1.0f / fmaxf((float)(end - start), 1.0f);
    const bool  empty = (end <= start);

    __shared__ float pl[512];
    #pragma unroll
    for (int e0 = 0; e0 < 2; ++e0) {
        const int e = j + e0 * 256;
        const int t = e >> 8, i = e & 255;
        const float* q = pp + (size_t)(g * 2 + t) * NS * 256 + i;
        float v;
        if (i < 128)
            v = fmaxf(fmaxf(q[0], q[256]), fmaxf(q[512], q[768]));
        else
            v = (q[0] + q[256] + q[512] + q[768]) * inv;
        pl[e] = empty ? 0.f : v;
    }
    __syncthreads();

    float acc = b1[j];
    #pragma unroll 8
    for (int k = 0; k < 256; ++k)          // t_max,t_mean -> W1 rows 128..383
        acc += pl[k] * W1[(size_t)(128 + k) * 256 + j];
    #pragma unroll 8
    for (int k = 0; k < 256; ++k)          // g_max,g_mean -> W1 rows 512..767
        acc += pl[256 + k] * W1[(size_t)(512 + k) * 256 + j];

    P[(size_t)g * 256 + j] = acc;
}

// ---------------------------------------------------------------------------
// Kernel 3: weight pre-convert to transposed bf16.
// ---------------------------------------------------------------------------
__global__ __launch_bounds__(256) void wconv_kernel(
    const float* __restrict__ W1, const float* __restrict__ W2,
    unsigned short* __restrict__ W1bT, unsigned short* __restrict__ W2bT)
{
    const int idx = blockIdx.x * 256 + threadIdx.x;
    if (idx < 256 * 256) {
        const int n = idx >> 8, k = idx & 255;
        const int kk = (k < 128) ? k : (k + 256);
        W1bT[idx] = f2bf(W1[(size_t)kk * 256 + n]);
    } else {
        const int j = idx - 256 * 256;
        if (j < 128 * 256) {
            const int n = j >> 8, k = j & 255;
            W2bT[j] = f2bf(W2[(size_t)k * 128 + n]);
        }
    }
}

// ---------------------------------------------------------------------------
// Kernel 4: fused MFMA MLP. 128 nodes/block, 8 waves (512 thr).
// X staged by reading h_topo/h_geom f32 DIRECTLY (L3-resident after pool),
// converting in-register (v_cvt_pk_bf16_f32), ds_write_b128 to the swizzled
// LDS image — no xt intermediate, no 102MB HBM round-trip.
// W1/W2 read from L2 once per 128 nodes; dist-2 register weight pipeline.
// ---------------------------------------------------------------------------
__global__ __launch_bounds__(512, 4) void mlp_mfma(
    const float* __restrict__ h_topo, const float* __restrict__ h_geom,
    const int* __restrict__ batch, const float* __restrict__ P,
    const unsigned short* __restrict__ W1bT, const unsigned short* __restrict__ W2bT,
    const float* __restrict__ b2, float* __restrict__ out, int N)
{
    __shared__ unsigned short xs[128 * 256];   // 64 KB, X then H (swz128 layout)
    __shared__ int gid[128];

    const int tid  = threadIdx.x;
    const int wave = tid >> 6, lane = tid & 63;
    const int base = blockIdx.x * BN;

    // ---- stage X: row = tid>>2 (0..127), kq = tid&3 (64-dim chunk) ----
    {
        const int row  = tid >> 2, kq = tid & 3;
        const int node = min(base + row, N - 1);
        const float* src = (kq < 2) ? h_topo + (size_t)node * D + kq * 64
                                    : h_geom + (size_t)node * D + (kq - 2) * 64;
        #pragma unroll
        for (int i = 0; i < 8; ++i) {
            float4 a = ((const float4*)src)[2 * i];
            float4 b = ((const float4*)src)[2 * i + 1];
            *(bf16x8*)&xs[swz128(row, kq * 64 + i * 8)] = cvt8(a, b);
        }
    }
    if (tid < 128) gid[tid] = batch[min(base + tid, N - 1)];

    const int g0 = batch[base];
    const int g1 = batch[min(base + 127, N - 1)];
    const bool uni = (g0 == g1);

    const int lhi = lane >> 4;   // 0..3
    const int llo = lane & 15;   // 0..15

    const unsigned short* w1p = W1bT + (size_t)(wave * 32 + llo) * 256 + lhi * 8;
    const unsigned short* w2p = W2bT + (size_t)(wave * 16 + llo) * 256 + lhi * 8;

    float pf[2];
    if (uni) {
        #pragma unroll
        for (int ct = 0; ct < 2; ++ct)
            pf[ct] = P[(size_t)g0 * 256 + wave * 32 + ct * 16 + llo];
    }

    // ---- preload GEMM1 ks=0,1 weight frags (stay pending across barrier) ----
    bf16x8 bfr[2][2];
    #pragma unroll
    for (int ct = 0; ct < 2; ++ct) {
        bfr[0][ct] = *(const bf16x8*)(w1p + (size_t)ct * 16 * 256);
        bfr[1][ct] = *(const bf16x8*)(w1p + (size_t)ct * 16 * 256 + 32);
    }

    LDS_BARRIER();   // X image published (lgkm only; weight vm loads in flight)

    // ---- GEMM1: 8 row-tiles x 2 col-tiles, dist-2 W prefetch ----
    f32x4 acc[8][2];
    #pragma unroll
    for (int rt = 0; rt < 8; ++rt)
        #pragma unroll
        for (int ct = 0; ct < 2; ++ct) {
            const float p = uni ? pf[ct] : 0.f;
            acc[rt][ct] = (f32x4){p, p, p, p};
        }

    #pragma unroll
    for (int ks = 0; ks < 8; ++ks) {
        const int kb = ks * 32 + lhi * 8;
        bf16x8 afr[8];
        #pragma unroll
        for (int rt = 0; rt < 8; ++rt)
            afr[rt] = *(const bf16x8*)&xs[swz128(rt * 16 + llo, kb)];
        __builtin_amdgcn_s_setprio(1);
        #pragma unroll
        for (int rt = 0; rt < 8; ++rt)
            #pragma unroll
            for (int ct = 0; ct < 2; ++ct)
                acc[rt][ct] = __builtin_amdgcn_mfma_f32_16x16x32_bf16(
                    afr[rt], bfr[ks & 1][ct], acc[rt][ct], 0, 0, 0);
        __builtin_amdgcn_s_setprio(0);
        if (ks < 6) {
            const int kbn = (ks + 2) * 32;
            #pragma unroll
            for (int ct = 0; ct < 2; ++ct)
                bfr[ks & 1][ct] = *(const bf16x8*)(w1p + (size_t)ct * 16 * 256 + kbn);
        }
    }

    // ---- issue GEMM2 ks=0,1 weight frags (in flight across barriers) ----
    bf16x8 bfr2[2];
    bfr2[0] = *(const bf16x8*)(w2p);
    bfr2[1] = *(const bf16x8*)(w2p + 32);

    LDS_BARRIER();   // all waves done reading X (lgkm only)

    // ---- epilogue 1: (+P if boundary tile), LeakyReLU, H -> xs (bf16) ----
    #pragma unroll
    for (int rt = 0; rt < 8; ++rt) {
        #pragma unroll
        for (int ct = 0; ct < 2; ++ct) {
            const int col = wave * 32 + ct * 16 + llo;
            #pragma unroll
            for (int q = 0; q < 4; ++q) {
                const int row = rt * 16 + lhi * 4 + q;
                float v = acc[rt][ct][q];
                if (!uni) v += P[(size_t)gid[row] * 256 + col];
                v = fmaxf(v, NEG * v);   // LeakyReLU
                xs[swz128(row, col)] = f2bf(v);
            }
        }
    }

    LDS_BARRIER();   // H published

    // ---- GEMM2: 8 row-tiles x 1 col-tile (16 cols/wave), dist-2 prefetch ----
    f32x4 acc2[8];
    {
        const float bv = b2[wave * 16 + llo];
        #pragma unroll
        for (int rt = 0; rt < 8; ++rt)
            acc2[rt] = (f32x4){bv, bv, bv, bv};
    }
    #pragma unroll
    for (int ks = 0; ks < 8; ++ks) {
        const int kb = ks * 32 + lhi * 8;
        bf16x8 afr[8];
        #pragma unroll
        for (int rt = 0; rt < 8; ++rt)
            afr[rt] = *(const bf16x8*)&xs[swz128(rt * 16 + llo, kb)];
        __builtin_amdgcn_s_setprio(1);
        #pragma unroll
        for (int rt = 0; rt < 8; ++rt)
            acc2[rt] = __builtin_amdgcn_mfma_f32_16x16x32_bf16(
                afr[rt], bfr2[ks & 1], acc2[rt], 0, 0, 0);
        __builtin_amdgcn_s_setprio(0);
        if (ks < 6)
            bfr2[ks & 1] = *(const bf16x8*)(w2p + (ks + 2) * 32);
    }

    // ---- store out (f32) ----
    #pragma unroll
    for (int rt = 0; rt < 8; ++rt)
        #pragma unroll
        for (int q = 0; q < 4; ++q) {
            const int row  = rt * 16 + lhi * 4 + q;
            const int node = base + row;
            if (node < N)
                out[(size_t)node * 128 + wave * 16 + llo] = acc2[rt][q];
        }
}

// ---------------------------------------------------------------------------
extern "C" void kernel_launch(void* const* d_in, const int* in_sizes, int n_in,
                              void* d_out, int out_size, void* d_ws, size_t ws_size,
                              hipStream_t stream)
{
    const float* h_topo = (const float*)d_in[0];
    const float* h_geom = (const float*)d_in[1];
    const int*   batch  = (const int*)  d_in[2];
    const float* W1     = (const float*)d_in[3];
    const float* b1     = (const float*)d_in[4];
    const float* W2     = (const float*)d_in[5];
    const float* b2     = (const float*)d_in[6];
    float* out = (float*)d_out;

    const int N = in_sizes[0] / D;   // 200000

    // ws layout: pp (4MB) | P (512KB) | W1bT | W2bT | seg (~2KB)
    float*          pp   = (float*)d_ws;
    float*          P    = pp + (size_t)NUM_GRAPHS * 2 * NS * 256;
    unsigned short* W1bT = (unsigned short*)(P + (size_t)NUM_GRAPHS * 256);
    unsigned short* W2bT = W1bT + 256 * 256;
    int*            seg  = (int*)(W2bT + 128 * 256);

    bounds_kernel<<<3, 256, 0, stream>>>(batch, N, seg);
    wconv_kernel<<<(256 * 256 + 128 * 256) / 256, 256, 0, stream>>>(W1, W2, W1bT, W2bT);
    pool_kernel<<<dim3(NUM_GRAPHS, 2, NS), 256, 0, stream>>>(h_topo, h_geom, seg, N, pp);
    pmat_kernel<<<NUM_GRAPHS, 256, 0, stream>>>(pp, seg, W1, b1, P);

    const int nblocks = (N + BN - 1) / BN;   // 1563
    mlp_mfma<<<nblocks, 512, 0, stream>>>(h_topo, h_geom, batch, P,
                                          W1bT, W2bT, b2, out, N);
}

// Round 12
// 169.371 us; speedup vs baseline: 1.2811x; 1.1376x over previous
//
#include <hip/hip_runtime.h>
#include <math.h>

#define NUM_GRAPHS 512
#define D 128
#define NEG 0.01f
#define BN 128  // nodes per block in MFMA MLP kernel
#define NS 4    // pool row-slices per (graph, tensor)

typedef __attribute__((ext_vector_type(8))) short  bf16x8;  // MFMA A/B frag
typedef __attribute__((ext_vector_type(4))) float  f32x4;   // MFMA C/D frag
typedef __attribute__((ext_vector_type(4))) int    i32x4;

__device__ __forceinline__ unsigned short f2bf(float f) {
    unsigned u = __float_as_uint(f);
    u += 0x7fffu + ((u >> 16) & 1u);   // RNE
    return (unsigned short)(u >> 16);
}

// f32x8 -> 16B of bf16 via packed cvt
__device__ __forceinline__ bf16x8 cvt8(float4 a, float4 b) {
    unsigned w0, w1, w2, w3;
    asm("v_cvt_pk_bf16_f32 %0, %1, %2" : "=v"(w0) : "v"(a.x), "v"(a.y));
    asm("v_cvt_pk_bf16_f32 %0, %1, %2" : "=v"(w1) : "v"(a.z), "v"(a.w));
    asm("v_cvt_pk_bf16_f32 %0, %1, %2" : "=v"(w2) : "v"(b.x), "v"(b.y));
    asm("v_cvt_pk_bf16_f32 %0, %1, %2" : "=v"(w3) : "v"(b.z), "v"(b.w));
    i32x4 v; v[0] = (int)w0; v[1] = (int)w1; v[2] = (int)w2; v[3] = (int)w3;
    return __builtin_bit_cast(bf16x8, v);
}

// swizzled ushort index in the 128-row two-tile LDS image
__device__ __forceinline__ int swz128(int row, int k) {
    return (row >> 6) * 16384 + (row & 63) * 256 + (k ^ ((row & 7) << 3));
}

// raw barrier that does NOT drain vmcnt (keeps global prefetch in flight);
// lgkmcnt(0) publishes LDS writes / retires LDS reads.
#define LDS_BARRIER()                                                        \
    do {                                                                     \
        asm volatile("s_waitcnt lgkmcnt(0)" ::: "memory");                   \
        __builtin_amdgcn_s_barrier();                                        \
        asm volatile("" ::: "memory");                                       \
    } while (0)

#define FMAX4(a, b)                                                          \
    do {                                                                     \
        (a).x = fmaxf((a).x, (b).x); (a).y = fmaxf((a).y, (b).y);            \
        (a).z = fmaxf((a).z, (b).z); (a).w = fmaxf((a).w, (b).w);            \
    } while (0)
#define FADD4(a, b)                                                          \
    do {                                                                     \
        (a).x += (b).x; (a).y += (b).y; (a).z += (b).z; (a).w += (b).w;      \
    } while (0)

// ---------------------------------------------------------------------------
// Kernel 0: segment bounds. seg[g] = lower_bound(batch, g), g in [0, 512].
// ---------------------------------------------------------------------------
__global__ __launch_bounds__(256) void bounds_kernel(
    const int* __restrict__ batch, int N, int* __restrict__ seg)
{
    const int g = blockIdx.x * 256 + threadIdx.x;
    if (g <= NUM_GRAPHS) {
        int lo = 0, hi = N;
        while (lo < hi) { int m = (lo + hi) >> 1; if (batch[m] < g) lo = m + 1; else hi = m; }
        seg[g] = lo;
    }
}

// ---------------------------------------------------------------------------
// Kernel 1: sliced per-graph segment max+sum partials (pure reduction).
// grid=(512, 2, NS); 4 independent acc streams for MLP.
// pp[((g*2+t)*NS+s)*256 + {0..127: max, 128..255: sum}]
// ---------------------------------------------------------------------------
__global__ __launch_bounds__(256) void pool_kernel(
    const float* __restrict__ h_topo, const float* __restrict__ h_geom,
    const int* __restrict__ seg, int N, float* __restrict__ pp)
{
    const int g = blockIdx.x, t = blockIdx.y, s = blockIdx.z;
    const float* __restrict__ h = t ? h_geom : h_topo;

    const int start = seg[g], end = seg[g + 1];
    const int len = end - start;
    const int r0  = start + (int)(((long long)len * s) / NS);
    const int r1  = start + (int)(((long long)len * (s + 1)) / NS);

    const int c = threadIdx.x & 31;   // float4 column
    const int r = threadIdx.x >> 5;   // 0..7 row phase

    float4 mxA = make_float4(-INFINITY, -INFINITY, -INFINITY, -INFINITY);
    float4 mxB = mxA, mxC = mxA, mxD = mxA;
    float4 smA = make_float4(0.f, 0.f, 0.f, 0.f);
    float4 smB = smA, smC = smA, smD = smA;

    int row = r0 + r;
    for (; row + 24 < r1; row += 32) {
        float4 v0 = *(const float4*)(h + (size_t)row * D + c * 4);
        float4 v1 = *(const float4*)(h + (size_t)(row + 8)  * D + c * 4);
        float4 v2 = *(const float4*)(h + (size_t)(row + 16) * D + c * 4);
        float4 v3 = *(const float4*)(h + (size_t)(row + 24) * D + c * 4);
        FMAX4(mxA, v0); FADD4(smA, v0);
        FMAX4(mxB, v1); FADD4(smB, v1);
        FMAX4(mxC, v2); FADD4(smC, v2);
        FMAX4(mxD, v3); FADD4(smD, v3);
    }
    for (; row < r1; row += 8) {
        float4 v = *(const float4*)(h + (size_t)row * D + c * 4);
        FMAX4(mxA, v); FADD4(smA, v);
    }
    FMAX4(mxA, mxB); FMAX4(mxC, mxD); FMAX4(mxA, mxC);
    FADD4(smA, smB); FADD4(smC, smD); FADD4(smA, smC);

    __shared__ float4 smx[256], ssm[256];
    smx[threadIdx.x] = mxA; ssm[threadIdx.x] = smA;
    __syncthreads();
    #pragma unroll
    for (int st = 4; st > 0; st >>= 1) {
        if (r < st) {
            float4 a = smx[threadIdx.x + st * 32];
            float4 b = ssm[threadIdx.x + st * 32];
            float4 m0 = smx[threadIdx.x];
            float4 s0 = ssm[threadIdx.x];
            FMAX4(m0, a); FADD4(s0, b);
            smx[threadIdx.x] = m0; ssm[threadIdx.x] = s0;
        }
        __syncthreads();
    }
    if (r == 0) {
        float* dst = pp + ((size_t)(g * 2 + t) * NS + s) * 256;
        *(float4*)(dst + c * 4)       = smx[threadIdx.x];   // raw max partial
        *(float4*)(dst + 128 + c * 4) = ssm[threadIdx.x];   // raw sum partial
    }
}

// ---------------------------------------------------------------------------
// Kernel 2: finalize partials + per-graph bias
// P[g][j] = b1[j] + pooled[g] . W1[pooled rows][j]
// ---------------------------------------------------------------------------
__global__ __launch_bounds__(256) void pmat_kernel(
    const float* __restrict__ pp, const int* __restrict__ seg,
    const float* __restrict__ W1, const float* __restrict__ b1,
    float* __restrict__ P)
{
    const int g = blockIdx.x;
    const int j = threadIdx.x;

    const int start = seg[g], end = seg[g + 1];
    const float inv   = 1.0f / fmaxf((float)(end - start), 1.0f);
    const bool  empty = (end <= start);

    __shared__ float pl[512];
    #pragma unroll
    for (int e0 = 0; e0 < 2; ++e0) {
        const int e = j + e0 * 256;
        const int t = e >> 8, i = e & 255;
        const float* q = pp + (size_t)(g * 2 + t) * NS * 256 + i;
        float v;
        if (i < 128)
            v = fmaxf(fmaxf(q[0], q[256]), fmaxf(q[512], q[768]));
        else
            v = (q[0] + q[256] + q[512] + q[768]) * inv;
        pl[e] = empty ? 0.f : v;
    }
    __syncthreads();

    float acc = b1[j];
    #pragma unroll 8
    for (int k = 0; k < 256; ++k)          // t_max,t_mean -> W1 rows 128..383
        acc += pl[k] * W1[(size_t)(128 + k) * 256 + j];
    #pragma unroll 8
    for (int k = 0; k < 256; ++k)          // g_max,g_mean -> W1 rows 512..767
        acc += pl[256 + k] * W1[(size_t)(512 + k) * 256 + j];

    P[(size_t)g * 256 + j] = acc;
}

// ---------------------------------------------------------------------------
// Kernel 3: weight pre-convert to transposed bf16.
// ---------------------------------------------------------------------------
__global__ __launch_bounds__(256) void wconv_kernel(
    const float* __restrict__ W1, const float* __restrict__ W2,
    unsigned short* __restrict__ W1bT, unsigned short* __restrict__ W2bT)
{
    const int idx = blockIdx.x * 256 + threadIdx.x;
    if (idx < 256 * 256) {
        const int n = idx >> 8, k = idx & 255;
        const int kk = (k < 128) ? k : (k + 256);
        W1bT[idx] = f2bf(W1[(size_t)kk * 256 + n]);
    } else {
        const int j = idx - 256 * 256;
        if (j < 128 * 256) {
            const int n = j >> 8, k = j & 255;
            W2bT[j] = f2bf(W2[(size_t)k * 128 + n]);
        }
    }
}

// ---------------------------------------------------------------------------
// Kernel 4: fused MFMA MLP. 128 nodes/block, 8 waves (512 thr).
// X staged by reading h_topo/h_geom f32 directly (L3-resident after pool),
// converted in-register. GEMM2 computed TRANSPOSED (A=W2 frag, B=H frag) so
// D = [j][node] and each lane stores a contiguous float4 of out, written with
// NON-TEMPORAL stores (bypass L2/L3 -> X stays L3-resident, no partial-line
// writeback amplification).
// ---------------------------------------------------------------------------
__global__ __launch_bounds__(512, 4) void mlp_mfma(
    const float* __restrict__ h_topo, const float* __restrict__ h_geom,
    const int* __restrict__ batch, const float* __restrict__ P,
    const unsigned short* __restrict__ W1bT, const unsigned short* __restrict__ W2bT,
    const float* __restrict__ b2, float* __restrict__ out, int N)
{
    __shared__ unsigned short xs[128 * 256];   // 64 KB, X then H (swz128 layout)
    __shared__ int gid[128];

    const int tid  = threadIdx.x;
    const int wave = tid >> 6, lane = tid & 63;
    const int base = blockIdx.x * BN;

    // ---- stage X: row = tid>>2 (0..127), kq = tid&3 (64-dim chunk) ----
    {
        const int row  = tid >> 2, kq = tid & 3;
        const int node = min(base + row, N - 1);
        const float* src = (kq < 2) ? h_topo + (size_t)node * D + kq * 64
                                    : h_geom + (size_t)node * D + (kq - 2) * 64;
        #pragma unroll
        for (int i = 0; i < 8; ++i) {
            float4 a = ((const float4*)src)[2 * i];
            float4 b = ((const float4*)src)[2 * i + 1];
            *(bf16x8*)&xs[swz128(row, kq * 64 + i * 8)] = cvt8(a, b);
        }
    }
    if (tid < 128) gid[tid] = batch[min(base + tid, N - 1)];

    const int g0 = batch[base];
    const int g1 = batch[min(base + 127, N - 1)];
    const bool uni = (g0 == g1);

    const int lhi = lane >> 4;   // 0..3
    const int llo = lane & 15;   // 0..15

    const unsigned short* w1p = W1bT + (size_t)(wave * 32 + llo) * 256 + lhi * 8;
    const unsigned short* w2p = W2bT + (size_t)(wave * 16 + llo) * 256 + lhi * 8;

    float pf[2];
    if (uni) {
        #pragma unroll
        for (int ct = 0; ct < 2; ++ct)
            pf[ct] = P[(size_t)g0 * 256 + wave * 32 + ct * 16 + llo];
    }

    // ---- preload GEMM1 ks=0,1 weight frags (stay pending across barrier) ----
    bf16x8 bfr[2][2];
    #pragma unroll
    for (int ct = 0; ct < 2; ++ct) {
        bfr[0][ct] = *(const bf16x8*)(w1p + (size_t)ct * 16 * 256);
        bfr[1][ct] = *(const bf16x8*)(w1p + (size_t)ct * 16 * 256 + 32);
    }

    LDS_BARRIER();   // X image published (lgkm only; weight vm loads in flight)

    // ---- GEMM1: 8 row-tiles x 2 col-tiles, dist-2 W prefetch ----
    f32x4 acc[8][2];
    #pragma unroll
    for (int rt = 0; rt < 8; ++rt)
        #pragma unroll
        for (int ct = 0; ct < 2; ++ct) {
            const float p = uni ? pf[ct] : 0.f;
            acc[rt][ct] = (f32x4){p, p, p, p};
        }

    #pragma unroll
    for (int ks = 0; ks < 8; ++ks) {
        const int kb = ks * 32 + lhi * 8;
        bf16x8 afr[8];
        #pragma unroll
        for (int rt = 0; rt < 8; ++rt)
            afr[rt] = *(const bf16x8*)&xs[swz128(rt * 16 + llo, kb)];
        __builtin_amdgcn_s_setprio(1);
        #pragma unroll
        for (int rt = 0; rt < 8; ++rt)
            #pragma unroll
            for (int ct = 0; ct < 2; ++ct)
                acc[rt][ct] = __builtin_amdgcn_mfma_f32_16x16x32_bf16(
                    afr[rt], bfr[ks & 1][ct], acc[rt][ct], 0, 0, 0);
        __builtin_amdgcn_s_setprio(0);
        if (ks < 6) {
            const int kbn = (ks + 2) * 32;
            #pragma unroll
            for (int ct = 0; ct < 2; ++ct)
                bfr[ks & 1][ct] = *(const bf16x8*)(w1p + (size_t)ct * 16 * 256 + kbn);
        }
    }

    // ---- issue GEMM2 ks=0,1 W2 frags (in flight across barriers) ----
    bf16x8 bfr2[2];
    bfr2[0] = *(const bf16x8*)(w2p);
    bfr2[1] = *(const bf16x8*)(w2p + 32);

    LDS_BARRIER();   // all waves done reading X (lgkm only)

    // ---- epilogue 1: (+P if boundary tile), LeakyReLU, H -> xs (bf16) ----
    #pragma unroll
    for (int rt = 0; rt < 8; ++rt) {
        #pragma unroll
        for (int ct = 0; ct < 2; ++ct) {
            const int col = wave * 32 + ct * 16 + llo;
            #pragma unroll
            for (int q = 0; q < 4; ++q) {
                const int row = rt * 16 + lhi * 4 + q;
                float v = acc[rt][ct][q];
                if (!uni) v += P[(size_t)gid[row] * 256 + col];
                v = fmaxf(v, NEG * v);   // LeakyReLU
                xs[swz128(row, col)] = f2bf(v);
            }
        }
    }

    LDS_BARRIER();   // H published

    // ---- GEMM2 (transposed): D[j][node] = W2T . H^T ----
    // A-frag = W2bT row j=wave*16+llo (w2p);  B-frag = H row node=rt*16+llo
    // (identical xs read pattern as GEMM1's A-frag). Lane stores out[node]
    // [wave*16+lhi*4 .. +4) as one float4 -> coalesced 64B chunks, NT.
    f32x4 acc2[8];
    {
        const float4 bb = *(const float4*)(b2 + wave * 16 + lhi * 4);
        #pragma unroll
        for (int rt = 0; rt < 8; ++rt)
            acc2[rt] = (f32x4){bb.x, bb.y, bb.z, bb.w};
    }
    #pragma unroll
    for (int ks = 0; ks < 8; ++ks) {
        const int kb = ks * 32 + lhi * 8;
        bf16x8 hfr[8];
        #pragma unroll
        for (int rt = 0; rt < 8; ++rt)
            hfr[rt] = *(const bf16x8*)&xs[swz128(rt * 16 + llo, kb)];
        __builtin_amdgcn_s_setprio(1);
        #pragma unroll
        for (int rt = 0; rt < 8; ++rt)
            acc2[rt] = __builtin_amdgcn_mfma_f32_16x16x32_bf16(
                bfr2[ks & 1], hfr[rt], acc2[rt], 0, 0, 0);
        __builtin_amdgcn_s_setprio(0);
        if (ks < 6)
            bfr2[ks & 1] = *(const bf16x8*)(w2p + (ks + 2) * 32);
    }

    // ---- store out: per-lane float4, non-temporal ----
    #pragma unroll
    for (int rt = 0; rt < 8; ++rt) {
        const int node = base + rt * 16 + llo;
        if (node < N)
            __builtin_nontemporal_store(
                acc2[rt],
                (f32x4*)(out + (size_t)node * 128 + wave * 16 + lhi * 4));
    }
}

// ---------------------------------------------------------------------------
extern "C" void kernel_launch(void* const* d_in, const int* in_sizes, int n_in,
                              void* d_out, int out_size, void* d_ws, size_t ws_size,
                              hipStream_t stream)
{
    const float* h_topo = (const float*)d_in[0];
    const float* h_geom = (const float*)d_in[1];
    const int*   batch  = (const int*)  d_in[2];
    const float* W1     = (const float*)d_in[3];
    const float* b1     = (const float*)d_in[4];
    const float* W2     = (const float*)d_in[5];
    const float* b2     = (const float*)d_in[6];
    float* out = (float*)d_out;

    const int N = in_sizes[0] / D;   // 200000

    // ws layout: pp (4MB) | P (512KB) | W1bT | W2bT | seg (~2KB)
    float*          pp   = (float*)d_ws;
    float*          P    = pp + (size_t)NUM_GRAPHS * 2 * NS * 256;
    unsigned short* W1bT = (unsigned short*)(P + (size_t)NUM_GRAPHS * 256);
    unsigned short* W2bT = W1bT + 256 * 256;
    int*            seg  = (int*)(W2bT + 128 * 256);

    bounds_kernel<<<3, 256, 0, stream>>>(batch, N, seg);
    wconv_kernel<<<(256 * 256 + 128 * 256) / 256, 256, 0, stream>>>(W1, W2, W1bT, W2bT);
    pool_kernel<<<dim3(NUM_GRAPHS, 2, NS), 256, 0, stream>>>(h_topo, h_geom, seg, N, pp);
    pmat_kernel<<<NUM_GRAPHS, 256, 0, stream>>>(pp, seg, W1, b1, P);

    const int nblocks = (N + BN - 1) / BN;   // 1563
    mlp_mfma<<<nblocks, 512, 0, stream>>>(h_topo, h_geom, batch, P,
                                          W1bT, W2bT, b2, out, N);
}